// Round 9
// baseline (5825.228 us; speedup 1.0000x reference)
//
#include <hip/hip_runtime.h>
#include <hip/hip_cooperative_groups.h>

namespace cg = cooperative_groups;

// ---------------- problem constants ----------------
static constexpr int B  = 4;
static constexpr int N0 = 2048;
static constexpr int LF = 8;
static constexpr int M1 = 1024, M2 = 512, M3 = 256;
static constexpr int O1 = 64, O2 = 128, O3 = 256;
static constexpr int NS1 = 12, NS2 = 8, NS3 = 4, NSQ = 4;
static constexpr int C1 = 67, C2 = 195, C3 = 387;
// All sampled-xyz arrays share this per-batch stride; levels 2/3 are PREFIXES
// of the level-1 FPS output (FPS hierarchical consistency, bit-exact since r6).
static constexpr long XS = 3 * (long)M1;
static constexpr int GRID = 256;  // cooperative grid: 256 blocks x 256 thr (1/CU)

// Exact float32 squared distance in numpy's op order ((dx^2+dy^2)+dz^2);
// _rn intrinsics forbid FMA contraction (discrete decisions depend on it).
__device__ __forceinline__ float sq3(float ax, float ay, float az,
                                     float bx, float by, float bz) {
  float dx = __fsub_rn(ax, bx), dy = __fsub_rn(ay, by), dz = __fsub_rn(az, bz);
  return __fadd_rn(__fadd_rn(__fmul_rn(dx, dx), __fmul_rn(dy, dy)),
                   __fmul_rn(dz, dz));
}

template <int CTRL>
__device__ __forceinline__ void dpp_max_step(unsigned& hi, unsigned& lo) {
  unsigned ohi = (unsigned)__builtin_amdgcn_update_dpp((int)hi, (int)hi, CTRL, 0xf, 0xf, false);
  unsigned olo = (unsigned)__builtin_amdgcn_update_dpp((int)lo, (int)lo, CTRL, 0xf, 0xf, false);
  bool take = (ohi > hi) || (ohi == hi && olo > lo);
  hi = take ? ohi : hi;
  lo = take ? olo : lo;
}

// ---------------- furthest point sampling v8: fps5 structure + slim k-loop ----
// Rounds 3-8 A/B: barrier (605us) <= spin (659) ~= owner-publish (660) — keep
// the fps5 barrier structure. Diet: in-loop track only (dist bits, k) with
// strict '>' over ascending k (first occurrence preserved), build the 11-bit
// index key after the loop. Tie-break matches jnp.argmax bit-exactly.
template <int N, int NPOINT>
__global__ __launch_bounds__(256, 1) void fps8(const float* __restrict__ pts,
                                               long s1, long s2,
                                               float* __restrict__ out,
                                               long o1, long o2) {
  constexpr int K = N / 256;
  const float* p = pts + (long)blockIdx.x * s1 + (long)blockIdx.y * s2;
  float* outb = out + (long)blockIdx.x * o1 + (long)blockIdx.y * o2;
  const int tid = threadIdx.x;
  const int lane = tid & 63;
  const int wid = tid >> 6;
  __shared__ float4 sp[N];
  __shared__ float sel[NPOINT * 3];
  __shared__ unsigned long long wbest[2][4];
  float ppx[K], ppy[K], ppz[K], dist[K];
#pragma unroll
  for (int k = 0; k < K; ++k) {
    const int j = k * 256 + tid;
    const float x = p[3 * j + 0], y = p[3 * j + 1], z = p[3 * j + 2];
    ppx[k] = x; ppy[k] = y; ppz[k] = z;
    sp[j] = make_float4(x, y, z, 0.f);
    dist[k] = 1e10f;
  }
  __syncthreads();
  const float4 c0 = sp[0];
  float lx = c0.x, ly = c0.y, lz = c0.z;  // first selected point = index 0
  for (int i = 0; i < NPOINT; ++i) {
    if (tid == 0) {
      sel[3 * i + 0] = lx; sel[3 * i + 1] = ly; sel[3 * i + 2] = lz;
    }
    unsigned bhi = 0u;
    int bk = 0;
#pragma unroll
    for (int k = 0; k < K; ++k) {
      const float d = sq3(ppx[k], ppy[k], ppz[k], lx, ly, lz);
      const float dm = fminf(dist[k], d);
      dist[k] = dm;
      const unsigned h = __float_as_uint(dm);  // dm>=0 => bits order-monotonic
      const bool take = h > bhi;               // strict > keeps smallest k on tie
      bhi = take ? h : bhi;
      bk = take ? k : bk;
    }
    unsigned blo = 2047u - (unsigned)(bk * 256 + tid);  // bigger = smaller idx
    dpp_max_step<0x111>(bhi, blo);
    dpp_max_step<0x112>(bhi, blo);
    dpp_max_step<0x114>(bhi, blo);
    dpp_max_step<0x118>(bhi, blo);
    dpp_max_step<0x142>(bhi, blo);
    dpp_max_step<0x143>(bhi, blo);
    if (lane == 63)
      wbest[i & 1][wid] = ((unsigned long long)bhi << 32) | blo;
    __syncthreads();
    unsigned long long gk = 0ull;
#pragma unroll
    for (int w = 0; w < 4; ++w) {
      const unsigned long long e = wbest[i & 1][w];
      gk = (e > gk) ? e : gk;
    }
    const int gidx = 2047 - (int)(gk & 0x7FFull);
    const float4 c = sp[gidx];  // broadcast ds_read_b128
    lx = c.x; ly = c.y; lz = c.z;
  }
  __syncthreads();
  for (int e = tid; e < NPOINT * 3; e += 256) outb[e] = sel[e];
}

// ---------------- wave-parallel ball query (first ns in-range, ascending) ----
// Ballot + prefix-popcount preserves exact reference semantics. Same-wave LDS
// RAW is in-order on CDNA (DS pipe processes a wave's ops in issue order).
template <int NS>
__device__ __forceinline__ void wave_bq(float qx, float qy, float qz,
                                        const float* __restrict__ src, int Ns,
                                        float r2, int* __restrict__ sidx, int lane) {
  int cnt = 0;
  for (int base = 0; base < Ns && cnt < NS; base += 64) {
    const int j = base + lane;
    bool in = false;
    if (j < Ns)
      in = sq3(qx, qy, qz, src[3 * j], src[3 * j + 1], src[3 * j + 2]) < r2;
    const unsigned long long mask = __ballot(in);
    const int pos = cnt + (int)__popcll(mask & ((1ull << lane) - 1ull));
    if (in && pos < NS) sidx[pos] = j;
    cnt += (int)__popcll(mask);
  }
  const int cc = cnt < NS ? cnt : NS;
  const int fill = (cc > 0) ? sidx[0] : 0;
  if (lane >= cc && lane < NS) sidx[lane] = fill;
}

// ---------------- one full timestep as a cooperative kernel ----------------
struct StepArgs {
  const float* x1c;   // current sampled xyz (stride XS; levels 2/3 = prefixes)
  const float* x1p;   // previous sampled xyz
  const float *W1, *W2, *W3;
  const float *S1p, *S2p, *S3p;
  float *S1c, *S2c, *S3c;
  float* frame;
  int *ii2, *ii1, *ii0;
  float *iw2, *iw1, *iw0;
  float *l3, *l2;
  const float *mw1, *mb1, *mw2, *mb2;
  float* out;
  int td, decode;
  float r2c1, r2q2, r2c2, r2q3, r2c3;
};

// Phases (grid.sync between): A: cell1 (per-wave units) + knn(all 3 levels);
// B: cell2 (per-128 units, feat-bq fused); C: cell3 (per-block, feat-bq fused);
// D: interpcat l3; E: interpcat l2; F: mlp (per-wave units) + frame update.
// All unit counts divide the grid evenly => uniform __syncthreads counts per
// block; decode is grid-uniform => uniform grid.sync sequence. Deadlock-free.
__global__ __launch_bounds__(256, 1) void step_kernel(StepArgs a) {
  __shared__ float smem[3272];  // max over phases: A=3264, B=3272, C=1684, F=2048 words
  cg::grid_group grid = cg::this_grid();
  const int tid = threadIdx.x;
  const int lane = tid & 63;
  const int wave = tid >> 6;

  // ================= Phase A: cell level-1 (+ knn for decode) ================
  {
    float* corr = smem + (size_t)wave * 816;  // 804 corr + 12 sidx
    int* sidx = (int*)(corr + 804);
    for (int u = blockIdx.x * 4 + wave; u < B * M1; u += GRID * 4) {  // 4 iters
      const int b = u >> 10, m = u & (M1 - 1);
      const float* p1 = a.x1c + (long)b * XS + 3 * m;
      const float p1x = p1[0], p1y = p1[1], p1z = p1[2];
      const float* p2b = a.x1p + (long)b * XS;
      wave_bq<NS1>(p1x, p1y, p1z, p2b, M1, a.r2c1, sidx, lane);
      __builtin_amdgcn_wave_barrier();
      for (int e = lane; e < C1 * NS1; e += 64) {
        const int c = e / NS1, s = e - c * NS1;
        const int j = sidx[s];
        float v;
        if (c < O1) {
          v = a.S1p[((long)b * O1 + c) * M1 + j];
        } else {
          const int d = c - O1;
          v = __fsub_rn(p2b[3 * j + d], (d == 0) ? p1x : ((d == 1) ? p1y : p1z));
        }
        corr[e] = v;
      }
      __builtin_amdgcn_wave_barrier();
      const int o = lane;
      const float* w = a.W1 + (long)o * C1;
      float accs[NS1];
#pragma unroll
      for (int s = 0; s < NS1; ++s) accs[s] = 0.f;
      for (int c = 0; c < C1; ++c) {
        const float wc = w[c];
        const float* cs = corr + c * NS1;
#pragma unroll
        for (int s = 0; s < NS1; ++s) accs[s] = fmaf(wc, cs[s], accs[s]);
      }
      float best = accs[0];
#pragma unroll
      for (int s = 1; s < NS1; ++s) best = fmaxf(best, accs[s]);
      a.S1c[((long)b * O1 + o) * M1 + m] = best;
    }
    if (a.decode) {  // all three 3-NN levels, grid-stride (no barriers)
      const int total = B * (M2 + M1 + N0);
      for (int t0 = blockIdx.x * 256 + tid; t0 < total; t0 += GRID * 256) {
        int t = t0;
        const float* unk; long ustr; int Mu, Mk; int* oi; float* ow;
        if (t < B * M2) {
          unk = a.x1c; ustr = XS; Mu = M2; Mk = M3; oi = a.ii2; ow = a.iw2;
        } else if (t < B * (M2 + M1)) {
          t -= B * M2;
          unk = a.x1c; ustr = XS; Mu = M1; Mk = M2; oi = a.ii1; ow = a.iw1;
        } else {
          t -= B * (M2 + M1);
          unk = a.frame; ustr = 3L * N0; Mu = N0; Mk = M1; oi = a.ii0; ow = a.iw0;
        }
        const int b = t / Mu, m = t - b * Mu;
        const float* q = unk + (long)b * ustr + (long)m * 3;
        const float qx = q[0], qy = q[1], qz = q[2];
        const float* s = a.x1c + (long)b * XS;
        float d0 = 3e38f, d1 = 3e38f, d2v = 3e38f;
        int i0 = 0, i1 = 0, i2 = 0;
        for (int j = 0; j < Mk; ++j) {
          float dd = sq3(qx, qy, qz, s[3 * j], s[3 * j + 1], s[3 * j + 2]);
          if (dd < d0) {
            d2v = d1; i2 = i1; d1 = d0; i1 = i0; d0 = dd; i0 = j;
          } else if (dd < d1) {
            d2v = d1; i2 = i1; d1 = dd; i1 = j;
          } else if (dd < d2v) {
            d2v = dd; i2 = j;
          }
        }
        float r0 = 1.0f / __fadd_rn(d0, 1e-8f);
        float r1 = 1.0f / __fadd_rn(d1, 1e-8f);
        float r2 = 1.0f / __fadd_rn(d2v, 1e-8f);
        float sum = __fadd_rn(__fadd_rn(r0, r1), r2);
        ow[t * 3 + 0] = r0 / sum;
        ow[t * 3 + 1] = r1 / sum;
        ow[t * 3 + 2] = r2 / sum;
        oi[t * 3 + 0] = i0;
        oi[t * 3 + 1] = i1;
        oi[t * 3 + 2] = i2;
      }
    }
  }
  grid.sync();

  // ================= Phase B: cell level-2 (feat ball-query fused) ===========
  {
    const int half = tid >> 7;
    const int ht = tid & 127;
    const int hw = (tid >> 6) & 1;
    float* base = smem + (size_t)half * 1636;
    float* corr = base;                  // 1560
    int* sidx = (int*)(base + 1560);     // 8
    int* sfidx = (int*)(base + 1568);    // 4
    float* feat = base + 1572;           // 64
    for (int u = blockIdx.x * 2 + half; u < B * M2; u += GRID * 2) {  // 4 iters
      const int b = u >> 9, m = u & (M2 - 1);
      const float* p1 = a.x1c + (long)b * XS + 3 * m;
      const float p1x = p1[0], p1y = p1[1], p1z = p1[2];
      const float* p2b = a.x1p + (long)b * XS;
      if (hw == 0)
        wave_bq<NS2>(p1x, p1y, p1z, p2b, M2, a.r2c2, sidx, lane);
      else
        wave_bq<NSQ>(p1x, p1y, p1z, a.x1c + (long)b * XS, M1, a.r2q2, sfidx, lane);
      __syncthreads();
      if (ht < O1) {
        const float* fb = a.S1c + ((long)b * O1 + ht) * M1;
        float bv = -3.0e38f;
#pragma unroll
        for (int s = 0; s < NSQ; ++s) bv = fmaxf(bv, fb[sfidx[s]]);
        feat[ht] = bv;
      }
      __syncthreads();
      for (int e = ht; e < C2 * NS2; e += 128) {
        const int c = e >> 3, s = e & 7;
        const int j = sidx[s];
        float v;
        if (c < O2) {
          v = a.S2p[((long)b * O2 + c) * M2 + j];
        } else if (c < O2 + O1) {
          v = feat[c - O2];
        } else {
          const int d = c - O2 - O1;
          v = __fsub_rn(p2b[3 * j + d], (d == 0) ? p1x : ((d == 1) ? p1y : p1z));
        }
        corr[e] = v;
      }
      __syncthreads();
      const int o = ht;
      const float* w = a.W2 + (long)o * C2;
      float accs[NS2];
#pragma unroll
      for (int s = 0; s < NS2; ++s) accs[s] = 0.f;
      for (int c = 0; c < C2; ++c) {
        const float wc = w[c];
        const float* cs = corr + c * NS2;
#pragma unroll
        for (int s = 0; s < NS2; ++s) accs[s] = fmaf(wc, cs[s], accs[s]);
      }
      float best = accs[0];
#pragma unroll
      for (int s = 1; s < NS2; ++s) best = fmaxf(best, accs[s]);
      a.S2c[((long)b * O2 + o) * M2 + m] = best;
    }
  }
  grid.sync();

  // ================= Phase C: cell level-3 (feat ball-query fused) ===========
  {
    float* corr = smem;                  // 1548
    int* sidx = (int*)(smem + 1548);     // 4
    int* sfidx = (int*)(smem + 1552);    // 4
    float* feat = smem + 1556;           // 128
    for (int u = blockIdx.x; u < B * M3; u += GRID) {  // 4 iters
      const int b = u >> 8, m = u & (M3 - 1);
      const float* p1 = a.x1c + (long)b * XS + 3 * m;
      const float p1x = p1[0], p1y = p1[1], p1z = p1[2];
      const float* p2b = a.x1p + (long)b * XS;
      if (wave == 0)
        wave_bq<NS3>(p1x, p1y, p1z, p2b, M3, a.r2c3, sidx, lane);
      else if (wave == 1)
        wave_bq<NSQ>(p1x, p1y, p1z, a.x1c + (long)b * XS, M2, a.r2q3, sfidx, lane);
      __syncthreads();
      if (tid < O2) {
        const float* fb = a.S2c + ((long)b * O2 + tid) * M2;
        float bv = -3.0e38f;
#pragma unroll
        for (int s = 0; s < NSQ; ++s) bv = fmaxf(bv, fb[sfidx[s]]);
        feat[tid] = bv;
      }
      __syncthreads();
      for (int e = tid; e < C3 * NS3; e += 256) {
        const int c = e >> 2, s = e & 3;
        const int j = sidx[s];
        float v;
        if (c < O3) {
          v = a.S3p[((long)b * O3 + c) * M3 + j];
        } else if (c < O3 + O2) {
          v = feat[c - O3];
        } else {
          const int d = c - O3 - O2;
          v = __fsub_rn(p2b[3 * j + d], (d == 0) ? p1x : ((d == 1) ? p1y : p1z));
        }
        corr[e] = v;
      }
      __syncthreads();
      const int o = tid;
      const float* w = a.W3 + (long)o * C3;
      float accs[NS3];
#pragma unroll
      for (int s = 0; s < NS3; ++s) accs[s] = 0.f;
      for (int c = 0; c < C3; ++c) {
        const float wc = w[c];
        const float* cs = corr + c * NS3;
#pragma unroll
        for (int s = 0; s < NS3; ++s) accs[s] = fmaf(wc, cs[s], accs[s]);
      }
      float best = accs[0];
#pragma unroll
      for (int s = 1; s < NS3; ++s) best = fmaxf(best, accs[s]);
      a.S3c[((long)b * O3 + o) * M3 + m] = best;
    }
  }

  if (a.decode) {
    grid.sync();
    // =============== Phase D: l3 = concat([interp(S3), S2]) ==================
    for (int t = blockIdx.x * 256 + tid; t < B * 384 * M2; t += GRID * 256) {
      const int m = t % M2;
      const int bc = t / M2;
      const int c = bc % 384;
      const int b = bc / 384;
      float v;
      if (c < O3) {
        const int* id = a.ii2 + ((long)b * M2 + m) * 3;
        const float* w = a.iw2 + ((long)b * M2 + m) * 3;
        const float* fb = a.S3c + ((long)b * O3 + c) * M3;
        v = __fadd_rn(__fadd_rn(__fmul_rn(fb[id[0]], w[0]), __fmul_rn(fb[id[1]], w[1])),
                      __fmul_rn(fb[id[2]], w[2]));
      } else {
        v = a.S2c[((long)b * O2 + (c - O3)) * M2 + m];
      }
      a.l3[t] = v;
    }
    grid.sync();
    // =============== Phase E: l2 = concat([interp(l3), S1]) ==================
    for (int t = blockIdx.x * 256 + tid; t < B * 448 * M1; t += GRID * 256) {
      const int m = t % M1;
      const int bc = t / M1;
      const int c = bc % 448;
      const int b = bc / 448;
      float v;
      if (c < 384) {
        const int* id = a.ii1 + ((long)b * M1 + m) * 3;
        const float* w = a.iw1 + ((long)b * M1 + m) * 3;
        const float* fb = a.l3 + ((long)b * 384 + c) * M2;
        v = __fadd_rn(__fadd_rn(__fmul_rn(fb[id[0]], w[0]), __fmul_rn(fb[id[1]], w[1])),
                      __fmul_rn(fb[id[2]], w[2]));
      } else {
        v = a.S1c[((long)b * O1 + (c - 384)) * M1 + m];
      }
      a.l2[t] = v;
    }
    grid.sync();
    // =============== Phase F: interp-to-l1 + MLP + frame update ==============
    {
      float* col = smem + (size_t)wave * 512;  // 448 col + 64 h
      float* h = col + 448;
      for (int u = blockIdx.x * 4 + wave; u < B * N0; u += GRID * 4) {  // 8 iters
        const int b = u >> 11, n = u & (N0 - 1);
        const int* id = a.ii0 + (long)u * 3;
        const float* w = a.iw0 + (long)u * 3;
        const float w0 = w[0], w1 = w[1], w2v = w[2];
        const int i0 = id[0], i1 = id[1], i2 = id[2];
        const float* l2b = a.l2 + (long)b * 448 * M1;
        for (int c = lane; c < 448; c += 64) {
          const float* r = l2b + (long)c * M1;
          col[c] = __fadd_rn(__fadd_rn(__fmul_rn(r[i0], w0), __fmul_rn(r[i1], w1)),
                             __fmul_rn(r[i2], w2v));
        }
        __builtin_amdgcn_wave_barrier();
        const int o = lane;
        const float* wr = a.mw1 + (long)o * 448;
        float acc = a.mb1[o];
        for (int c = 0; c < 448; ++c) acc = fmaf(wr[c], col[c], acc);
        h[o] = fmaxf(acc, 0.0f);
        __builtin_amdgcn_wave_barrier();
        if (o < 3) {
          const float* w2r = a.mw2 + o * 64;
          float acc2 = a.mb2[o];
          for (int c = 0; c < 64; ++c) acc2 = fmaf(w2r[c], h[c], acc2);
          const float nf = a.frame[(long)u * 3 + o] + acc2;
          a.frame[(long)u * 3 + o] = nf;
          a.out[(((long)b * 4 + a.td) * N0 + n) * 3 + o] = nf;
        }
        __builtin_amdgcn_wave_barrier();  // protect col/h reuse next unit
      }
    }
  }
}

__global__ __launch_bounds__(256) void copyframe_kernel(const float* __restrict__ xyzs,
                                                        float* __restrict__ frame,
                                                        int total) {
  int t = blockIdx.x * 256 + threadIdx.x;
  if (t >= total) return;
  int b = t / (N0 * 3);
  int rr = t - b * (N0 * 3);
  frame[t] = xyzs[((long)b * LF + (LF / 2 - 1)) * (N0 * 3) + rr];
}

extern "C" void kernel_launch(void* const* d_in, const int* in_sizes, int n_in,
                              void* d_out, int out_size, void* d_ws, size_t ws_size,
                              hipStream_t stream) {
  const float* xyzs = (const float*)d_in[0];
  const float* enw[3] = {(const float*)d_in[1], (const float*)d_in[2], (const float*)d_in[3]};
  const float* dew[3] = {(const float*)d_in[4], (const float*)d_in[5], (const float*)d_in[6]};
  const float* mw1 = (const float*)d_in[7];
  const float* mb1 = (const float*)d_in[8];
  const float* mw2 = (const float*)d_in[9];
  const float* mb2 = (const float*)d_in[10];
  float* out = (float*)d_out;

  float* ws = (float*)d_ws;
  size_t off = 0;
  auto alloc = [&](size_t nn) { float* p = ws + off; off += nn; return p; };
  const long st1 = (long)B * M1 * 3;
  float* frame = alloc((size_t)B * N0 * 3);
  float* xyz1e = alloc((size_t)4 * st1);  // encoder t=0..3 (levels 2/3 = prefixes)
  float* xyz1d[2] = {alloc((size_t)st1), alloc((size_t)st1)};  // decoder t=5..7
  float* z1 = alloc((size_t)st1);
  float* S1bf[2] = {alloc((size_t)B * O1 * M1), alloc((size_t)B * O1 * M1)};
  float* S2bf[2] = {alloc((size_t)B * O2 * M2), alloc((size_t)B * O2 * M2)};
  float* S3bf[2] = {alloc((size_t)B * O3 * M3), alloc((size_t)B * O3 * M3)};
  float* l3 = alloc((size_t)B * 384 * M2);
  float* l2 = alloc((size_t)B * 448 * M1);
  float* iw0 = alloc((size_t)B * N0 * 3);
  int* ii0 = (int*)alloc((size_t)B * N0 * 3);
  float* iw1 = alloc((size_t)B * M1 * 3);
  int* ii1 = (int*)alloc((size_t)B * M1 * 3);
  float* iw2 = alloc((size_t)B * M2 * 3);
  int* ii2 = (int*)alloc((size_t)B * M2 * 3);

  hipMemsetAsync(z1, 0, (size_t)st1 * 4, stream);
  hipMemsetAsync(S1bf[1], 0, (size_t)B * O1 * M1 * 4, stream);
  hipMemsetAsync(S2bf[1], 0, (size_t)B * O2 * M2 * 4, stream);
  hipMemsetAsync(S3bf[1], 0, (size_t)B * O3 * M3 * 4, stream);

  double r;
  r = 4.0 + 1e-6;             const float r2c1 = (float)(r * r);
  r = 2.0 * 4.0 / 4.0 + 1e-6; const float r2q2 = (float)(r * r);
  r = 2.0 * 4.0 + 1e-6;       const float r2c2 = (float)(r * r);
  r = 4.0 * 4.0 / 4.0 + 1e-6; const float r2q3 = (float)(r * r);
  r = 3.0 * 4.0 + 1e-6;       const float r2c3 = (float)(r * r);

  // batched encoder FPS (level 1 only; levels 2/3 are prefixes)
  fps8<2048, 1024><<<dim3(B, 4), 256, 0, stream>>>(xyzs, (long)LF * N0 * 3, (long)N0 * 3,
                                                   xyz1e, XS, st1);

  // t=4: frame == xyzs[:,3] bit-exactly => fps(frame) == encoder t=3's result.
  const float* x1_of_t[LF] = {
      xyz1e + 0 * st1, xyz1e + 1 * st1, xyz1e + 2 * st1, xyz1e + 3 * st1,
      xyz1e + 3 * st1, xyz1d[0], xyz1d[1], xyz1d[0]};

  for (int t = 0; t < LF; ++t) {
    const bool enc = t < LF / 2;
    const int cur = t & 1, prev = 1 - cur;
    if (t == LF / 2)
      copyframe_kernel<<<dim3((B * N0 * 3 + 255) / 256), 256, 0, stream>>>(
          xyzs, frame, B * N0 * 3);
    const float* x1c = x1_of_t[t];
    const float* x1p = (t == 0) ? z1 : x1_of_t[t - 1];
    if (t > LF / 2)
      fps8<2048, 1024><<<dim3(B, 1), 256, 0, stream>>>(frame, (long)N0 * 3, 0,
                                                       (float*)x1c, XS, 0);
    StepArgs sa;
    sa.x1c = x1c; sa.x1p = x1p;
    sa.W1 = enc ? enw[0] : dew[0];
    sa.W2 = enc ? enw[1] : dew[1];
    sa.W3 = enc ? enw[2] : dew[2];
    sa.S1p = S1bf[prev]; sa.S2p = S2bf[prev]; sa.S3p = S3bf[prev];
    sa.S1c = S1bf[cur]; sa.S2c = S2bf[cur]; sa.S3c = S3bf[cur];
    sa.frame = frame;
    sa.ii2 = ii2; sa.ii1 = ii1; sa.ii0 = ii0;
    sa.iw2 = iw2; sa.iw1 = iw1; sa.iw0 = iw0;
    sa.l3 = l3; sa.l2 = l2;
    sa.mw1 = mw1; sa.mb1 = mb1; sa.mw2 = mw2; sa.mb2 = mb2;
    sa.out = out;
    sa.td = t - LF / 2;
    sa.decode = enc ? 0 : 1;
    sa.r2c1 = r2c1; sa.r2q2 = r2q2; sa.r2c2 = r2c2; sa.r2q3 = r2q3; sa.r2c3 = r2c3;
    void* params[] = {&sa};
    hipLaunchCooperativeKernel((const void*)step_kernel, dim3(GRID), dim3(256),
                               params, 0, stream);
  }
  (void)in_sizes; (void)n_in; (void)out_size; (void)ws_size;
}

// Round 10
// 4486.754 us; speedup vs baseline: 1.2983x; 1.2983x over previous
//
#include <hip/hip_runtime.h>

// ---------------- problem constants ----------------
static constexpr int B  = 4;
static constexpr int N0 = 2048;
static constexpr int LF = 8;
static constexpr int M1 = 1024, M2 = 512, M3 = 256;
static constexpr int O1 = 64, O2 = 128, O3 = 256;
static constexpr int NS1 = 12, NS2 = 8, NS3 = 4, NSQ = 4;
static constexpr int C1 = 67, C2 = 195, C3 = 387;
// All sampled-xyz arrays share this per-batch stride; levels 2/3 are PREFIXES
// of the level-1 FPS output (FPS hierarchical consistency, bit-exact since r6).
static constexpr long XS = 3 * (long)M1;

// Exact float32 squared distance in numpy's op order ((dx^2+dy^2)+dz^2);
// _rn intrinsics forbid FMA contraction (discrete decisions depend on it).
__device__ __forceinline__ float sq3(float ax, float ay, float az,
                                     float bx, float by, float bz) {
  float dx = __fsub_rn(ax, bx), dy = __fsub_rn(ay, by), dz = __fsub_rn(az, bz);
  return __fadd_rn(__fadd_rn(__fmul_rn(dx, dx), __fmul_rn(dy, dy)),
                   __fmul_rn(dz, dz));
}

template <int CTRL>
__device__ __forceinline__ void dpp_max_step(unsigned& hi, unsigned& lo) {
  unsigned ohi = (unsigned)__builtin_amdgcn_update_dpp((int)hi, (int)hi, CTRL, 0xf, 0xf, false);
  unsigned olo = (unsigned)__builtin_amdgcn_update_dpp((int)lo, (int)lo, CTRL, 0xf, 0xf, false);
  bool take = (ohi > hi) || (ohi == hi && olo > lo);
  hi = take ? ohi : hi;
  lo = take ? olo : lo;
}

// ---------------- furthest point sampling (fps5 structure + slim k-loop) -----
// Best measured family (r3-r9 A/B: barrier 605us <= spin 659 ~= owner 660).
// Tie-break first-occurrence via strict '>' ascending scan + lo = 2047-j,
// matching jnp.argmax bit-exactly. Encoder launch has grid (B,5): y==4 blocks
// do the frame copy (merged copyframe dispatch).
template <int N, int NPOINT>
__global__ __launch_bounds__(256, 1) void fps8(const float* __restrict__ pts,
                                               long s1, long s2,
                                               float* __restrict__ out,
                                               long o1, long o2,
                                               const float* __restrict__ cfsrc,
                                               float* __restrict__ cfdst,
                                               int copy_y) {
  if ((int)blockIdx.y == copy_y) {  // merged copyframe: frame[b] = xyzs[b, LF/2-1]
    const int b = blockIdx.x;
    for (int e = threadIdx.x; e < N0 * 3; e += 256)
      cfdst[(long)b * N0 * 3 + e] = cfsrc[((long)b * LF + (LF / 2 - 1)) * N0 * 3 + e];
    return;
  }
  constexpr int K = N / 256;
  const float* p = pts + (long)blockIdx.x * s1 + (long)blockIdx.y * s2;
  float* outb = out + (long)blockIdx.x * o1 + (long)blockIdx.y * o2;
  const int tid = threadIdx.x;
  const int lane = tid & 63;
  const int wid = tid >> 6;
  __shared__ float4 sp[N];
  __shared__ float sel[NPOINT * 3];
  __shared__ unsigned long long wbest[2][4];
  float ppx[K], ppy[K], ppz[K], dist[K];
#pragma unroll
  for (int k = 0; k < K; ++k) {
    const int j = k * 256 + tid;
    const float x = p[3 * j + 0], y = p[3 * j + 1], z = p[3 * j + 2];
    ppx[k] = x; ppy[k] = y; ppz[k] = z;
    sp[j] = make_float4(x, y, z, 0.f);
    dist[k] = 1e10f;
  }
  __syncthreads();
  const float4 c0 = sp[0];
  float lx = c0.x, ly = c0.y, lz = c0.z;  // first selected point = index 0
  for (int i = 0; i < NPOINT; ++i) {
    if (tid == 0) {
      sel[3 * i + 0] = lx; sel[3 * i + 1] = ly; sel[3 * i + 2] = lz;
    }
    unsigned bhi = 0u;
    int bk = 0;
#pragma unroll
    for (int k = 0; k < K; ++k) {
      const float d = sq3(ppx[k], ppy[k], ppz[k], lx, ly, lz);
      const float dm = fminf(dist[k], d);
      dist[k] = dm;
      const unsigned h = __float_as_uint(dm);  // dm>=0 => bits order-monotonic
      const bool take = h > bhi;               // strict > keeps smallest k on tie
      bhi = take ? h : bhi;
      bk = take ? k : bk;
    }
    unsigned blo = 2047u - (unsigned)(bk * 256 + tid);  // bigger = smaller idx
    dpp_max_step<0x111>(bhi, blo);
    dpp_max_step<0x112>(bhi, blo);
    dpp_max_step<0x114>(bhi, blo);
    dpp_max_step<0x118>(bhi, blo);
    dpp_max_step<0x142>(bhi, blo);
    dpp_max_step<0x143>(bhi, blo);
    if (lane == 63)
      wbest[i & 1][wid] = ((unsigned long long)bhi << 32) | blo;
    __syncthreads();
    unsigned long long gk = 0ull;
#pragma unroll
    for (int w = 0; w < 4; ++w) {
      const unsigned long long e = wbest[i & 1][w];
      gk = (e > gk) ? e : gk;
    }
    const int gidx = 2047 - (int)(gk & 0x7FFull);
    const float4 c = sp[gidx];  // broadcast ds_read_b128
    lx = c.x; ly = c.y; lz = c.z;
  }
  __syncthreads();
  for (int e = tid; e < NPOINT * 3; e += 256) outb[e] = sel[e];
}

// ---------------- wave-parallel ball query (first ns in-range, ascending) ----
template <int NS>
__device__ __forceinline__ void wave_bq(float qx, float qy, float qz,
                                        const float* __restrict__ src, int Ns,
                                        float r2, int* __restrict__ sidx, int lane) {
  int cnt = 0;
  for (int base = 0; base < Ns && cnt < NS; base += 64) {
    const int j = base + lane;
    bool in = false;
    if (j < Ns)
      in = sq3(qx, qy, qz, src[3 * j], src[3 * j + 1], src[3 * j + 2]) < r2;
    const unsigned long long mask = __ballot(in);
    const int pos = cnt + (int)__popcll(mask & ((1ull << lane) - 1ull));
    if (in && pos < NS) sidx[pos] = j;
    cnt += (int)__popcll(mask);
  }
  const int cc = cnt < NS ? cnt : NS;
  const int fill = (cc > 0) ? sidx[0] : 0;
  if (lane >= cc && lane < NS) sidx[lane] = fill;
}

// ---------------- fused multi-cell (+knn) dispatch ----------------
// Block ranges: [0,n1) cell1 (4 units/block, 1/wave); [n1,n1+n2) cell2
// (2 units/block, 128 thr each, feat-bq fused); [.., +n3) cell3 (1 unit/block,
// feat-bq fused); [.., +nk) knn (all 3 interp levels, 56 blocks exactly).
// Tasks within one dispatch are mutually independent (encoder pipeline:
// {c1(t), c2(t-1), c3(t-2)} — ping-pong parities all distinct). No grid-wide
// sync needed; dispatch boundaries are the barrier (r9 lesson: cooperative
// grid.sync costs ~100us in cross-XCD L2 flush traffic).
struct FusedArgs {
  int n1, n2, n3, nk;
  const float *c1_xc, *c1_xp, *c1_W, *c1_Sp; float* c1_Sc;
  const float *c2_xc, *c2_xp, *c2_W, *c2_Sp, *c2_S1; float* c2_Sc;
  const float *c3_xc, *c3_xp, *c3_W, *c3_Sp, *c3_S2; float* c3_Sc;
  const float *k_xc, *k_frame;
  int *ii2, *ii1, *ii0;
  float *iw2, *iw1, *iw0;
  float r2c1, r2c2, r2q2, r2c3, r2q3;
};

__global__ __launch_bounds__(256) void fused_cells(FusedArgs a) {
  __shared__ float smem[3272];
  const int tid = threadIdx.x;
  const int lane = tid & 63;
  const int wave = tid >> 6;
  int bid = blockIdx.x;

  if (bid < a.n1) {  // ---------------- cell level-1 ----------------
    float* corr = smem + (size_t)wave * 816;  // 804 corr + 12 sidx
    int* sidx = (int*)(corr + 804);
    const int u = bid * 4 + wave;
    const int b = u >> 10, m = u & (M1 - 1);
    const float* p1 = a.c1_xc + (long)b * XS + 3 * m;
    const float p1x = p1[0], p1y = p1[1], p1z = p1[2];
    const float* p2b = a.c1_xp + (long)b * XS;
    wave_bq<NS1>(p1x, p1y, p1z, p2b, M1, a.r2c1, sidx, lane);
    __builtin_amdgcn_wave_barrier();
    for (int e = lane; e < C1 * NS1; e += 64) {
      const int c = e / NS1, s = e - c * NS1;
      const int j = sidx[s];
      float v;
      if (c < O1) {
        v = a.c1_Sp[((long)b * O1 + c) * M1 + j];
      } else {
        const int d = c - O1;
        v = __fsub_rn(p2b[3 * j + d], (d == 0) ? p1x : ((d == 1) ? p1y : p1z));
      }
      corr[e] = v;
    }
    __builtin_amdgcn_wave_barrier();
    const float* w = a.c1_W + (long)lane * C1;
    float accs[NS1];
#pragma unroll
    for (int s = 0; s < NS1; ++s) accs[s] = 0.f;
    for (int c = 0; c < C1; ++c) {
      const float wc = w[c];
      const float* cs = corr + c * NS1;
#pragma unroll
      for (int s = 0; s < NS1; ++s) accs[s] = fmaf(wc, cs[s], accs[s]);
    }
    float best = accs[0];
#pragma unroll
    for (int s = 1; s < NS1; ++s) best = fmaxf(best, accs[s]);
    a.c1_Sc[((long)b * O1 + lane) * M1 + m] = best;
    return;
  }
  bid -= a.n1;

  if (bid < a.n2) {  // ---------------- cell level-2 ----------------
    const int half = tid >> 7;
    const int ht = tid & 127;
    const int hw = (tid >> 6) & 1;
    float* base = smem + (size_t)half * 1636;
    float* corr = base;                  // 1560
    int* sidx = (int*)(base + 1560);     // 8
    int* sfidx = (int*)(base + 1568);    // 4
    float* feat = base + 1572;           // 64
    const int u = bid * 2 + half;
    const int b = u >> 9, m = u & (M2 - 1);
    const float* p1 = a.c2_xc + (long)b * XS + 3 * m;
    const float p1x = p1[0], p1y = p1[1], p1z = p1[2];
    const float* p2b = a.c2_xp + (long)b * XS;
    if (hw == 0)
      wave_bq<NS2>(p1x, p1y, p1z, p2b, M2, a.r2c2, sidx, lane);
    else
      wave_bq<NSQ>(p1x, p1y, p1z, a.c2_xc + (long)b * XS, M1, a.r2q2, sfidx, lane);
    __syncthreads();
    if (ht < O1) {
      const float* fb = a.c2_S1 + ((long)b * O1 + ht) * M1;
      float bv = -3.0e38f;
#pragma unroll
      for (int s = 0; s < NSQ; ++s) bv = fmaxf(bv, fb[sfidx[s]]);
      feat[ht] = bv;
    }
    __syncthreads();
    for (int e = ht; e < C2 * NS2; e += 128) {
      const int c = e >> 3, s = e & 7;
      const int j = sidx[s];
      float v;
      if (c < O2) {
        v = a.c2_Sp[((long)b * O2 + c) * M2 + j];
      } else if (c < O2 + O1) {
        v = feat[c - O2];
      } else {
        const int d = c - O2 - O1;
        v = __fsub_rn(p2b[3 * j + d], (d == 0) ? p1x : ((d == 1) ? p1y : p1z));
      }
      corr[e] = v;
    }
    __syncthreads();
    const float* w = a.c2_W + (long)ht * C2;
    float accs[NS2];
#pragma unroll
    for (int s = 0; s < NS2; ++s) accs[s] = 0.f;
    for (int c = 0; c < C2; ++c) {
      const float wc = w[c];
      const float* cs = corr + c * NS2;
#pragma unroll
      for (int s = 0; s < NS2; ++s) accs[s] = fmaf(wc, cs[s], accs[s]);
    }
    float best = accs[0];
#pragma unroll
    for (int s = 1; s < NS2; ++s) best = fmaxf(best, accs[s]);
    a.c2_Sc[((long)b * O2 + ht) * M2 + m] = best;
    return;
  }
  bid -= a.n2;

  if (bid < a.n3) {  // ---------------- cell level-3 ----------------
    float* corr = smem;                  // 1548
    int* sidx = (int*)(smem + 1548);     // 4
    int* sfidx = (int*)(smem + 1552);    // 4
    float* feat = smem + 1556;           // 128
    const int u = bid;
    const int b = u >> 8, m = u & (M3 - 1);
    const float* p1 = a.c3_xc + (long)b * XS + 3 * m;
    const float p1x = p1[0], p1y = p1[1], p1z = p1[2];
    const float* p2b = a.c3_xp + (long)b * XS;
    if (wave == 0)
      wave_bq<NS3>(p1x, p1y, p1z, p2b, M3, a.r2c3, sidx, lane);
    else if (wave == 1)
      wave_bq<NSQ>(p1x, p1y, p1z, a.c3_xc + (long)b * XS, M2, a.r2q3, sfidx, lane);
    __syncthreads();
    if (tid < O2) {
      const float* fb = a.c3_S2 + ((long)b * O2 + tid) * M2;
      float bv = -3.0e38f;
#pragma unroll
      for (int s = 0; s < NSQ; ++s) bv = fmaxf(bv, fb[sfidx[s]]);
      feat[tid] = bv;
    }
    __syncthreads();
    for (int e = tid; e < C3 * NS3; e += 256) {
      const int c = e >> 2, s = e & 3;
      const int j = sidx[s];
      float v;
      if (c < O3) {
        v = a.c3_Sp[((long)b * O3 + c) * M3 + j];
      } else if (c < O3 + O2) {
        v = feat[c - O3];
      } else {
        const int d = c - O3 - O2;
        v = __fsub_rn(p2b[3 * j + d], (d == 0) ? p1x : ((d == 1) ? p1y : p1z));
      }
      corr[e] = v;
    }
    __syncthreads();
    const float* w = a.c3_W + (long)tid * C3;
    float accs[NS3];
#pragma unroll
    for (int s = 0; s < NS3; ++s) accs[s] = 0.f;
    for (int c = 0; c < C3; ++c) {
      const float wc = w[c];
      const float* cs = corr + c * NS3;
#pragma unroll
      for (int s = 0; s < NS3; ++s) accs[s] = fmaf(wc, cs[s], accs[s]);
    }
    float best = accs[0];
#pragma unroll
    for (int s = 1; s < NS3; ++s) best = fmaxf(best, accs[s]);
    a.c3_Sc[((long)b * O3 + tid) * M3 + m] = best;
    return;
  }
  bid -= a.n3;

  {  // ---------------- knn: all three interp levels (56 blocks exact) --------
    int t = bid * 256 + tid;  // in [0, 14336) = B*(M2+M1+N0)
    const float* unk; long ustr; int Mu, Mk; int* oi; float* ow;
    if (t < B * M2) {
      unk = a.k_xc; ustr = XS; Mu = M2; Mk = M3; oi = a.ii2; ow = a.iw2;
    } else if (t < B * (M2 + M1)) {
      t -= B * M2;
      unk = a.k_xc; ustr = XS; Mu = M1; Mk = M2; oi = a.ii1; ow = a.iw1;
    } else {
      t -= B * (M2 + M1);
      unk = a.k_frame; ustr = 3L * N0; Mu = N0; Mk = M1; oi = a.ii0; ow = a.iw0;
    }
    const int b = t / Mu, m = t - b * Mu;
    const float* q = unk + (long)b * ustr + (long)m * 3;
    const float qx = q[0], qy = q[1], qz = q[2];
    const float* s = a.k_xc + (long)b * XS;
    float d0 = 3e38f, d1 = 3e38f, d2v = 3e38f;
    int i0 = 0, i1 = 0, i2 = 0;
    for (int j = 0; j < Mk; ++j) {
      float dd = sq3(qx, qy, qz, s[3 * j], s[3 * j + 1], s[3 * j + 2]);
      if (dd < d0) {
        d2v = d1; i2 = i1; d1 = d0; i1 = i0; d0 = dd; i0 = j;
      } else if (dd < d1) {
        d2v = d1; i2 = i1; d1 = dd; i1 = j;
      } else if (dd < d2v) {
        d2v = dd; i2 = j;
      }
    }
    float r0 = 1.0f / __fadd_rn(d0, 1e-8f);
    float r1 = 1.0f / __fadd_rn(d1, 1e-8f);
    float r2 = 1.0f / __fadd_rn(d2v, 1e-8f);
    float sum = __fadd_rn(__fadd_rn(r0, r1), r2);
    ow[t * 3 + 0] = r0 / sum;
    ow[t * 3 + 1] = r1 / sum;
    ow[t * 3 + 2] = r2 / sum;
    oi[t * 3 + 0] = i0;
    oi[t * 3 + 1] = i1;
    oi[t * 3 + 2] = i2;
  }
}

// ---------------- buildl2: fused interpcat-D + interpcat-E (bit-exact) -------
// l2[b,c,m1]: c<256: interp1(interp2(S3c)) with v2_k computed by the IDENTICAL
// mul/add chain D would write to l3, then E's chain — bit-exact composition;
// 256<=c<384: interp1 of S2c (l3's copy region); c>=384: copy S1c.
__device__ __forceinline__ float interp3(const float* __restrict__ f, const int* id,
                                         const float* w) {
  return __fadd_rn(__fadd_rn(__fmul_rn(f[id[0]], w[0]), __fmul_rn(f[id[1]], w[1])),
                   __fmul_rn(f[id[2]], w[2]));
}

__global__ __launch_bounds__(256) void buildl2_kernel(const float* __restrict__ S3c,
                                                      const float* __restrict__ S2c,
                                                      const float* __restrict__ S1c,
                                                      const int* __restrict__ ii1,
                                                      const float* __restrict__ iw1,
                                                      const int* __restrict__ ii2,
                                                      const float* __restrict__ iw2,
                                                      float* __restrict__ l2) {
  const int t = blockIdx.x * 256 + threadIdx.x;  // exact: 7168*256 = B*448*M1
  const int m = t & (M1 - 1);
  const int bc = t >> 10;
  const int c = bc % 448;
  const int b = bc / 448;
  const int* id1 = ii1 + ((long)b * M1 + m) * 3;
  const float* w1 = iw1 + ((long)b * M1 + m) * 3;
  float v;
  if (c < O3) {
    const float* fb = S3c + ((long)b * O3 + c) * M3;
    float v2[3];
#pragma unroll
    for (int k = 0; k < 3; ++k) {
      const int m2 = id1[k];
      v2[k] = interp3(fb, ii2 + ((long)b * M2 + m2) * 3, iw2 + ((long)b * M2 + m2) * 3);
    }
    v = __fadd_rn(__fadd_rn(__fmul_rn(v2[0], w1[0]), __fmul_rn(v2[1], w1[1])),
                  __fmul_rn(v2[2], w1[2]));
  } else if (c < 384) {
    const float* fb = S2c + ((long)b * O2 + (c - O3)) * M2;
    v = interp3(fb, id1, w1);
  } else {
    v = S1c[((long)b * O1 + (c - 384)) * M1 + m];
  }
  l2[t] = v;
}

// ---------------- fused interp-to-l1 + 2-layer MLP + frame update ------------
__global__ __launch_bounds__(64) void mlp_kernel(const float* __restrict__ l2,
                                                 const int* __restrict__ ii,
                                                 const float* __restrict__ iw,
                                                 const float* __restrict__ W1,
                                                 const float* __restrict__ b1,
                                                 const float* __restrict__ W2,
                                                 const float* __restrict__ b2,
                                                 float* __restrict__ frame,
                                                 float* __restrict__ out, int td) {
  const int bn = blockIdx.x;
  const int b = bn / N0, n = bn - b * N0;
  __shared__ float col[448];
  __shared__ float h[64];
  const int* id = ii + (long)bn * 3;
  const float* w = iw + (long)bn * 3;
  const float w0 = w[0], w1 = w[1], w2v = w[2];
  const int i0 = id[0], i1 = id[1], i2 = id[2];
  const float* l2b = l2 + (long)b * 448 * M1;
  for (int c = threadIdx.x; c < 448; c += 64) {
    const float* r = l2b + (long)c * M1;
    col[c] = __fadd_rn(__fadd_rn(__fmul_rn(r[i0], w0), __fmul_rn(r[i1], w1)),
                       __fmul_rn(r[i2], w2v));
  }
  __syncthreads();
  const int o = threadIdx.x;
  const float* wr = W1 + (long)o * 448;
  float acc = b1[o];
  for (int c = 0; c < 448; ++c) acc = fmaf(wr[c], col[c], acc);
  h[o] = fmaxf(acc, 0.0f);
  __syncthreads();
  if (o < 3) {
    const float* w2r = W2 + o * 64;
    float acc2 = b2[o];
    for (int c = 0; c < 64; ++c) acc2 = fmaf(w2r[c], h[c], acc2);
    float nf = frame[(long)bn * 3 + o] + acc2;
    frame[(long)bn * 3 + o] = nf;
    out[(((long)b * 4 + td) * N0 + n) * 3 + o] = nf;
  }
}

extern "C" void kernel_launch(void* const* d_in, const int* in_sizes, int n_in,
                              void* d_out, int out_size, void* d_ws, size_t ws_size,
                              hipStream_t stream) {
  const float* xyzs = (const float*)d_in[0];
  const float* enw[3] = {(const float*)d_in[1], (const float*)d_in[2], (const float*)d_in[3]};
  const float* dew[3] = {(const float*)d_in[4], (const float*)d_in[5], (const float*)d_in[6]};
  const float* mw1 = (const float*)d_in[7];
  const float* mb1 = (const float*)d_in[8];
  const float* mw2 = (const float*)d_in[9];
  const float* mb2 = (const float*)d_in[10];
  float* out = (float*)d_out;

  float* ws = (float*)d_ws;
  size_t off = 0;
  auto alloc = [&](size_t nn) { float* p = ws + off; off += nn; return p; };
  const long st1 = (long)B * M1 * 3;
  float* frame = alloc((size_t)B * N0 * 3);
  float* xyz1e = alloc((size_t)4 * st1);  // encoder t=0..3 (levels 2/3 = prefixes)
  float* xyz1d[2] = {alloc((size_t)st1), alloc((size_t)st1)};  // decoder t=5..7
  float* z1 = alloc((size_t)st1);
  float* S1bf[2] = {alloc((size_t)B * O1 * M1), alloc((size_t)B * O1 * M1)};
  float* S2bf[2] = {alloc((size_t)B * O2 * M2), alloc((size_t)B * O2 * M2)};
  float* S3bf[2] = {alloc((size_t)B * O3 * M3), alloc((size_t)B * O3 * M3)};
  float* l2 = alloc((size_t)B * 448 * M1);
  float* iw0 = alloc((size_t)B * N0 * 3);
  int* ii0 = (int*)alloc((size_t)B * N0 * 3);
  float* iw1 = alloc((size_t)B * M1 * 3);
  int* ii1 = (int*)alloc((size_t)B * M1 * 3);
  float* iw2 = alloc((size_t)B * M2 * 3);
  int* ii2 = (int*)alloc((size_t)B * M2 * 3);

  hipMemsetAsync(z1, 0, (size_t)st1 * 4, stream);
  hipMemsetAsync(S1bf[1], 0, (size_t)B * O1 * M1 * 4, stream);
  hipMemsetAsync(S2bf[1], 0, (size_t)B * O2 * M2 * 4, stream);
  hipMemsetAsync(S3bf[1], 0, (size_t)B * O3 * M3 * 4, stream);

  double r;
  r = 4.0 + 1e-6;             const float r2c1 = (float)(r * r);
  r = 2.0 * 4.0 / 4.0 + 1e-6; const float r2q2 = (float)(r * r);
  r = 2.0 * 4.0 + 1e-6;       const float r2c2 = (float)(r * r);
  r = 4.0 * 4.0 / 4.0 + 1e-6; const float r2q3 = (float)(r * r);
  r = 3.0 * 4.0 + 1e-6;       const float r2c3 = (float)(r * r);

  // encoder FPS (all 4 timesteps) + merged copyframe: grid (B,5), y==4 copies
  fps8<2048, 1024><<<dim3(B, 5), 256, 0, stream>>>(xyzs, (long)LF * N0 * 3,
                                                   (long)N0 * 3, xyz1e, XS, st1,
                                                   xyzs, frame, 4);

  // t=4: frame == xyzs[:,3] bit-exactly => fps(frame) == encoder t=3's result.
  const float* x1_of_t[LF] = {
      xyz1e + 0 * st1, xyz1e + 1 * st1, xyz1e + 2 * st1, xyz1e + 3 * st1,
      xyz1e + 3 * st1, xyz1d[0], xyz1d[1], xyz1d[0]};

  auto launch_fused = [&](int t1, int t2, int t3, int tk) {
    FusedArgs a{};
    int nb = 0;
    if (t1 >= 0) {
      a.n1 = B * M1 / 4;
      a.c1_xc = x1_of_t[t1];
      a.c1_xp = (t1 == 0) ? z1 : x1_of_t[t1 - 1];
      a.c1_W = (t1 < 4 ? enw : dew)[0];
      a.c1_Sp = S1bf[1 - (t1 & 1)];
      a.c1_Sc = S1bf[t1 & 1];
      nb += a.n1;
    }
    if (t2 >= 0) {
      a.n2 = B * M2 / 2;
      a.c2_xc = x1_of_t[t2];
      a.c2_xp = (t2 == 0) ? z1 : x1_of_t[t2 - 1];
      a.c2_W = (t2 < 4 ? enw : dew)[1];
      a.c2_Sp = S2bf[1 - (t2 & 1)];
      a.c2_S1 = S1bf[t2 & 1];
      a.c2_Sc = S2bf[t2 & 1];
      nb += a.n2;
    }
    if (t3 >= 0) {
      a.n3 = B * M3;
      a.c3_xc = x1_of_t[t3];
      a.c3_xp = (t3 == 0) ? z1 : x1_of_t[t3 - 1];
      a.c3_W = (t3 < 4 ? enw : dew)[2];
      a.c3_Sp = S3bf[1 - (t3 & 1)];
      a.c3_S2 = S2bf[t3 & 1];
      a.c3_Sc = S3bf[t3 & 1];
      nb += a.n3;
    }
    if (tk >= 0) {
      a.nk = B * (M2 + M1 + N0) / 256;  // 56
      a.k_xc = x1_of_t[tk];
      a.k_frame = frame;
      a.ii2 = ii2; a.ii1 = ii1; a.ii0 = ii0;
      a.iw2 = iw2; a.iw1 = iw1; a.iw0 = iw0;
      nb += a.nk;
    }
    a.r2c1 = r2c1; a.r2c2 = r2c2; a.r2q2 = r2q2; a.r2c3 = r2c3; a.r2q3 = r2q3;
    fused_cells<<<dim3((unsigned)nb), 256, 0, stream>>>(a);
  };

  auto tail = [&](int t) {  // buildl2 + mlp for decoder timestep t
    buildl2_kernel<<<dim3(B * 448 * M1 / 256), 256, 0, stream>>>(
        S3bf[t & 1], S2bf[t & 1], S1bf[t & 1], ii1, iw1, ii2, iw2, l2);
    mlp_kernel<<<B * N0, 64, 0, stream>>>(l2, ii0, iw0, mw1, mb1, mw2, mb2, frame, out,
                                          t - 4);
  };

  // encoder software pipeline + t=4 head (all merges are independent tasks)
  launch_fused(0, -1, -1, -1);
  launch_fused(1, 0, -1, -1);
  launch_fused(2, 1, 0, -1);
  launch_fused(3, 2, 1, -1);
  launch_fused(4, 3, 2, 4);   // c1(4)+knn(4) need only D0 outputs; c2(3),c3(2) prior
  launch_fused(-1, 4, 3, -1);
  launch_fused(-1, -1, 4, -1);
  tail(4);

  for (int t = 5; t < LF; ++t) {
    fps8<2048, 1024><<<dim3(B, 1), 256, 0, stream>>>(frame, (long)N0 * 3, 0,
                                                     (float*)x1_of_t[t], XS, 0,
                                                     nullptr, nullptr, -1);
    launch_fused(t, -1, -1, t);
    launch_fused(-1, t, -1, -1);
    launch_fused(-1, -1, t, -1);
    tail(t);
  }
  (void)in_sizes; (void)n_in; (void)out_size; (void)ws_size;
}

// Round 11
// 3692.908 us; speedup vs baseline: 1.5774x; 1.2150x over previous
//
#include <hip/hip_runtime.h>

// ---------------- problem constants ----------------
static constexpr int B  = 4;
static constexpr int N0 = 2048;
static constexpr int LF = 8;
static constexpr int M1 = 1024, M2 = 512, M3 = 256;
static constexpr int O1 = 64, O2 = 128, O3 = 256;
static constexpr int NS1 = 12, NS2 = 8, NS3 = 4, NSQ = 4;
static constexpr int C1 = 67, C2 = 195, C3 = 387;
static constexpr long XS = 3 * (long)M1;  // xyz batch stride; L2/L3 = prefixes (r6)

// weight-transpose pool offsets (floats)
static constexpr int WT_E1 = 0, WT_E2 = 4288, WT_E3 = 29248;
static constexpr int WT_D1 = 128320, WT_D2 = 132608, WT_D3 = 157568;
static constexpr int WT_M1 = 256640, WT_TOT = 285312;

__device__ __forceinline__ float sq3(float ax, float ay, float az,
                                     float bx, float by, float bz) {
  float dx = __fsub_rn(ax, bx), dy = __fsub_rn(ay, by), dz = __fsub_rn(az, bz);
  return __fadd_rn(__fadd_rn(__fmul_rn(dx, dx), __fmul_rn(dy, dy)),
                   __fmul_rn(dz, dz));
}

template <int CTRL>
__device__ __forceinline__ void dpp_max_step(unsigned& hi, unsigned& lo) {
  unsigned ohi = (unsigned)__builtin_amdgcn_update_dpp((int)hi, (int)hi, CTRL, 0xf, 0xf, false);
  unsigned olo = (unsigned)__builtin_amdgcn_update_dpp((int)lo, (int)lo, CTRL, 0xf, 0xf, false);
  bool take = (ohi > hi) || (ohi == hi && olo > lo);
  hi = take ? ohi : hi;
  lo = take ? olo : lo;
}

// ---------------- weight transpose: W[o][c] -> WT[c][o] (bit-exact relayout) --
__global__ __launch_bounds__(256) void transpose_w(
    const float* __restrict__ e1, const float* __restrict__ e2,
    const float* __restrict__ e3, const float* __restrict__ d1,
    const float* __restrict__ d2, const float* __restrict__ d3,
    const float* __restrict__ m1, float* __restrict__ dst) {
  int t = blockIdx.x * 256 + threadIdx.x;
  const float* src; int C; long dof;
  if (t < WT_E2) { src = e1; C = C1; dof = WT_E1; t -= WT_E1; }
  else if (t < WT_E3) { src = e2; C = C2; dof = WT_E2; t -= WT_E2; }
  else if (t < WT_D1) { src = e3; C = C3; dof = WT_E3; t -= WT_E3; }
  else if (t < WT_D2) { src = d1; C = C1; dof = WT_D1; t -= WT_D1; }
  else if (t < WT_D3) { src = d2; C = C2; dof = WT_D2; t -= WT_D2; }
  else if (t < WT_M1) { src = d3; C = C3; dof = WT_D3; t -= WT_D3; }
  else if (t < WT_TOT) { src = m1; C = 448; dof = WT_M1; t -= WT_M1; }
  else return;
  const int O = (C == C1) ? O1 : (C == C2) ? O2 : (C == C3) ? O3 : 64;
  const int o = t / C, c = t - o * C;
  dst[dof + (long)c * O + o] = src[t];
}

// ---------------- furthest point sampling (fps8, best measured) --------------
template <int N, int NPOINT>
__global__ __launch_bounds__(256, 1) void fps8(const float* __restrict__ pts,
                                               long s1, long s2,
                                               float* __restrict__ out,
                                               long o1, long o2,
                                               const float* __restrict__ cfsrc,
                                               float* __restrict__ cfdst,
                                               int copy_y) {
  if ((int)blockIdx.y == copy_y) {  // merged copyframe
    const int b = blockIdx.x;
    for (int e = threadIdx.x; e < N0 * 3; e += 256)
      cfdst[(long)b * N0 * 3 + e] = cfsrc[((long)b * LF + (LF / 2 - 1)) * N0 * 3 + e];
    return;
  }
  constexpr int K = N / 256;
  const float* p = pts + (long)blockIdx.x * s1 + (long)blockIdx.y * s2;
  float* outb = out + (long)blockIdx.x * o1 + (long)blockIdx.y * o2;
  const int tid = threadIdx.x;
  const int lane = tid & 63;
  const int wid = tid >> 6;
  __shared__ float4 sp[N];
  __shared__ float sel[NPOINT * 3];
  __shared__ unsigned long long wbest[2][4];
  float ppx[K], ppy[K], ppz[K], dist[K];
#pragma unroll
  for (int k = 0; k < K; ++k) {
    const int j = k * 256 + tid;
    const float x = p[3 * j + 0], y = p[3 * j + 1], z = p[3 * j + 2];
    ppx[k] = x; ppy[k] = y; ppz[k] = z;
    sp[j] = make_float4(x, y, z, 0.f);
    dist[k] = 1e10f;
  }
  __syncthreads();
  const float4 c0 = sp[0];
  float lx = c0.x, ly = c0.y, lz = c0.z;
  for (int i = 0; i < NPOINT; ++i) {
    if (tid == 0) {
      sel[3 * i + 0] = lx; sel[3 * i + 1] = ly; sel[3 * i + 2] = lz;
    }
    unsigned bhi = 0u;
    int bk = 0;
#pragma unroll
    for (int k = 0; k < K; ++k) {
      const float d = sq3(ppx[k], ppy[k], ppz[k], lx, ly, lz);
      const float dm = fminf(dist[k], d);
      dist[k] = dm;
      const unsigned h = __float_as_uint(dm);
      const bool take = h > bhi;  // strict > keeps smallest k (first occurrence)
      bhi = take ? h : bhi;
      bk = take ? k : bk;
    }
    unsigned blo = 2047u - (unsigned)(bk * 256 + tid);
    dpp_max_step<0x111>(bhi, blo);
    dpp_max_step<0x112>(bhi, blo);
    dpp_max_step<0x114>(bhi, blo);
    dpp_max_step<0x118>(bhi, blo);
    dpp_max_step<0x142>(bhi, blo);
    dpp_max_step<0x143>(bhi, blo);
    if (lane == 63)
      wbest[i & 1][wid] = ((unsigned long long)bhi << 32) | blo;
    __syncthreads();
    unsigned long long gk = 0ull;
#pragma unroll
    for (int w = 0; w < 4; ++w) {
      const unsigned long long e = wbest[i & 1][w];
      gk = (e > gk) ? e : gk;
    }
    const int gidx = 2047 - (int)(gk & 0x7FFull);
    const float4 c = sp[gidx];
    lx = c.x; ly = c.y; lz = c.z;
  }
  __syncthreads();
  for (int e = tid; e < NPOINT * 3; e += 256) outb[e] = sel[e];
}

// ---------------- wave-parallel ball query (first ns in-range, ascending) ----
template <int NS>
__device__ __forceinline__ void wave_bq(float qx, float qy, float qz,
                                        const float* __restrict__ src, int Ns,
                                        float r2, int* __restrict__ sidx, int lane) {
  int cnt = 0;
  for (int base = 0; base < Ns && cnt < NS; base += 64) {
    const int j = base + lane;
    bool in = false;
    if (j < Ns)
      in = sq3(qx, qy, qz, src[3 * j], src[3 * j + 1], src[3 * j + 2]) < r2;
    const unsigned long long mask = __ballot(in);
    const int pos = cnt + (int)__popcll(mask & ((1ull << lane) - 1ull));
    if (in && pos < NS) sidx[pos] = j;
    cnt += (int)__popcll(mask);
  }
  const int cc = cnt < NS ? cnt : NS;
  const int fill = (cc > 0) ? sidx[0] : 0;
  if (lane >= cc && lane < NS) sidx[lane] = fill;
}

// ---------------- fused multi-cell (+knn) dispatch ----------------
// POINT-MAJOR S layout: S[b][m][ch] (coalesced stores: lane = channel) and
// TRANSPOSED weights WT[c][o] (coalesced loads: lane = o). corr staged s-major
// corr2[s][C]; compute keeps c-outer/s-inner FMA order => bit-identical.
struct FusedArgs {
  int n1, n2, n3, nk;
  const float *c1_xc, *c1_xp, *c1_W, *c1_Sp; float* c1_Sc;
  const float *c2_xc, *c2_xp, *c2_W, *c2_Sp, *c2_S1; float* c2_Sc;
  const float *c3_xc, *c3_xp, *c3_W, *c3_Sp, *c3_S2; float* c3_Sc;
  const float *k_xc, *k_frame;
  int *ii2, *ii1, *ii0;
  float *iw2, *iw1, *iw0;
  float r2c1, r2c2, r2q2, r2c3, r2q3;
};

__global__ __launch_bounds__(256) void fused_cells(FusedArgs a) {
  __shared__ float smem[3272];
  const int tid = threadIdx.x;
  const int lane = tid & 63;
  const int wave = tid >> 6;
  int bid = blockIdx.x;

  if (bid < a.n1) {  // -------- cell level-1 (4 wave-units/block) --------
    float* corr2 = smem + (size_t)wave * 816;  // [NS1][C1] = 804, +12 sidx
    int* sidx = (int*)(corr2 + 804);
    const int u = bid * 4 + wave;
    const int b = u >> 10, m = u & (M1 - 1);
    const float* p1 = a.c1_xc + (long)b * XS + 3 * m;
    const float p1x = p1[0], p1y = p1[1], p1z = p1[2];
    const float* p2b = a.c1_xp + (long)b * XS;
    wave_bq<NS1>(p1x, p1y, p1z, p2b, M1, a.r2c1, sidx, lane);
    __builtin_amdgcn_wave_barrier();
    for (int e = lane; e < NS1 * C1; e += 64) {
      const int s = e / C1, c = e - s * C1;
      const int j = sidx[s];
      float v;
      if (c < O1) {
        v = a.c1_Sp[((long)b * M1 + j) * O1 + c];  // point-major: coalesced in c
      } else {
        const int d = c - O1;
        v = __fsub_rn(p2b[3 * j + d], (d == 0) ? p1x : ((d == 1) ? p1y : p1z));
      }
      corr2[e] = v;
    }
    __builtin_amdgcn_wave_barrier();
    float accs[NS1];
#pragma unroll
    for (int s = 0; s < NS1; ++s) accs[s] = 0.f;
    for (int c = 0; c < C1; ++c) {
      const float wc = a.c1_W[(long)c * O1 + lane];  // WT: coalesced
#pragma unroll
      for (int s = 0; s < NS1; ++s) accs[s] = fmaf(wc, corr2[s * C1 + c], accs[s]);
    }
    float best = accs[0];
#pragma unroll
    for (int s = 1; s < NS1; ++s) best = fmaxf(best, accs[s]);
    a.c1_Sc[((long)b * M1 + m) * O1 + lane] = best;  // coalesced store
    return;
  }
  bid -= a.n1;

  if (bid < a.n2) {  // -------- cell level-2 (2 128-thr units/block) --------
    const int half = tid >> 7;
    const int ht = tid & 127;
    const int hw = (tid >> 6) & 1;
    float* base = smem + (size_t)half * 1636;
    float* corr2 = base;                 // [NS2][C2] = 1560
    int* sidx = (int*)(base + 1560);     // 8
    int* sfidx = (int*)(base + 1568);    // 4
    float* feat = base + 1572;           // 64
    const int u = bid * 2 + half;
    const int b = u >> 9, m = u & (M2 - 1);
    const float* p1 = a.c2_xc + (long)b * XS + 3 * m;
    const float p1x = p1[0], p1y = p1[1], p1z = p1[2];
    const float* p2b = a.c2_xp + (long)b * XS;
    if (hw == 0)
      wave_bq<NS2>(p1x, p1y, p1z, p2b, M2, a.r2c2, sidx, lane);
    else
      wave_bq<NSQ>(p1x, p1y, p1z, a.c2_xc + (long)b * XS, M1, a.r2q2, sfidx, lane);
    __syncthreads();
    if (ht < O1) {
      float bv = -3.0e38f;
#pragma unroll
      for (int s = 0; s < NSQ; ++s)
        bv = fmaxf(bv, a.c2_S1[((long)b * M1 + sfidx[s]) * O1 + ht]);  // coalesced
      feat[ht] = bv;
    }
    __syncthreads();
    for (int e = ht; e < NS2 * C2; e += 128) {
      const int s = e / C2, c = e - s * C2;
      const int j = sidx[s];
      float v;
      if (c < O2) {
        v = a.c2_Sp[((long)b * M2 + j) * O2 + c];
      } else if (c < O2 + O1) {
        v = feat[c - O2];
      } else {
        const int d = c - O2 - O1;
        v = __fsub_rn(p2b[3 * j + d], (d == 0) ? p1x : ((d == 1) ? p1y : p1z));
      }
      corr2[e] = v;
    }
    __syncthreads();
    float accs[NS2];
#pragma unroll
    for (int s = 0; s < NS2; ++s) accs[s] = 0.f;
    for (int c = 0; c < C2; ++c) {
      const float wc = a.c2_W[(long)c * O2 + ht];
#pragma unroll
      for (int s = 0; s < NS2; ++s) accs[s] = fmaf(wc, corr2[s * C2 + c], accs[s]);
    }
    float best = accs[0];
#pragma unroll
    for (int s = 1; s < NS2; ++s) best = fmaxf(best, accs[s]);
    a.c2_Sc[((long)b * M2 + m) * O2 + ht] = best;
    return;
  }
  bid -= a.n2;

  if (bid < a.n3) {  // -------- cell level-3 (1 unit/block, 256 thr) --------
    float* corr2 = smem;                 // [NS3][C3] = 1548
    int* sidx = (int*)(smem + 1548);
    int* sfidx = (int*)(smem + 1552);
    float* feat = smem + 1556;           // 128
    const int b = bid >> 8, m = bid & (M3 - 1);
    const float* p1 = a.c3_xc + (long)b * XS + 3 * m;
    const float p1x = p1[0], p1y = p1[1], p1z = p1[2];
    const float* p2b = a.c3_xp + (long)b * XS;
    if (wave == 0)
      wave_bq<NS3>(p1x, p1y, p1z, p2b, M3, a.r2c3, sidx, lane);
    else if (wave == 1)
      wave_bq<NSQ>(p1x, p1y, p1z, a.c3_xc + (long)b * XS, M2, a.r2q3, sfidx, lane);
    __syncthreads();
    if (tid < O2) {
      float bv = -3.0e38f;
#pragma unroll
      for (int s = 0; s < NSQ; ++s)
        bv = fmaxf(bv, a.c3_S2[((long)b * M2 + sfidx[s]) * O2 + tid]);
      feat[tid] = bv;
    }
    __syncthreads();
    for (int e = tid; e < NS3 * C3; e += 256) {
      const int s = e / C3, c = e - s * C3;
      const int j = sidx[s];
      float v;
      if (c < O3) {
        v = a.c3_Sp[((long)b * M3 + j) * O3 + c];
      } else if (c < O3 + O2) {
        v = feat[c - O3];
      } else {
        const int d = c - O3 - O2;
        v = __fsub_rn(p2b[3 * j + d], (d == 0) ? p1x : ((d == 1) ? p1y : p1z));
      }
      corr2[e] = v;
    }
    __syncthreads();
    float accs[NS3];
#pragma unroll
    for (int s = 0; s < NS3; ++s) accs[s] = 0.f;
    for (int c = 0; c < C3; ++c) {
      const float wc = a.c3_W[(long)c * O3 + tid];
#pragma unroll
      for (int s = 0; s < NS3; ++s) accs[s] = fmaf(wc, corr2[s * C3 + c], accs[s]);
    }
    float best = accs[0];
#pragma unroll
    for (int s = 1; s < NS3; ++s) best = fmaxf(best, accs[s]);
    a.c3_Sc[((long)b * M3 + m) * O3 + tid] = best;
    return;
  }
  bid -= a.n3;

  {  // -------- knn: all three interp levels (56 blocks exact) --------
    int t = bid * 256 + tid;
    const float* unk; long ustr; int Mu, Mk; int* oi; float* ow;
    if (t < B * M2) {
      unk = a.k_xc; ustr = XS; Mu = M2; Mk = M3; oi = a.ii2; ow = a.iw2;
    } else if (t < B * (M2 + M1)) {
      t -= B * M2;
      unk = a.k_xc; ustr = XS; Mu = M1; Mk = M2; oi = a.ii1; ow = a.iw1;
    } else {
      t -= B * (M2 + M1);
      unk = a.k_frame; ustr = 3L * N0; Mu = N0; Mk = M1; oi = a.ii0; ow = a.iw0;
    }
    const int b = t / Mu, m = t - b * Mu;
    const float* q = unk + (long)b * ustr + (long)m * 3;
    const float qx = q[0], qy = q[1], qz = q[2];
    const float* s = a.k_xc + (long)b * XS;
    float d0 = 3e38f, d1 = 3e38f, d2v = 3e38f;
    int i0 = 0, i1 = 0, i2 = 0;
    for (int j = 0; j < Mk; ++j) {
      float dd = sq3(qx, qy, qz, s[3 * j], s[3 * j + 1], s[3 * j + 2]);
      if (dd < d0) {
        d2v = d1; i2 = i1; d1 = d0; i1 = i0; d0 = dd; i0 = j;
      } else if (dd < d1) {
        d2v = d1; i2 = i1; d1 = dd; i1 = j;
      } else if (dd < d2v) {
        d2v = dd; i2 = j;
      }
    }
    float r0 = 1.0f / __fadd_rn(d0, 1e-8f);
    float r1 = 1.0f / __fadd_rn(d1, 1e-8f);
    float r2 = 1.0f / __fadd_rn(d2v, 1e-8f);
    float sum = __fadd_rn(__fadd_rn(r0, r1), r2);
    ow[t * 3 + 0] = r0 / sum;
    ow[t * 3 + 1] = r1 / sum;
    ow[t * 3 + 2] = r2 / sum;
    oi[t * 3 + 0] = i0;
    oi[t * 3 + 1] = i1;
    oi[t * 3 + 2] = i2;
  }
}

// ---------------- buildl2 (point-major, coalesced) ----------------
// l2T[b][m][448]; c<256: bit-exact composed interp1(interp2(S3)); 256..384:
// interp1(S2); >=384: copy S1. A wave spans 64 consecutive c of one (b,m)
// (448 = 7 waves) => id1/iw1 wave-uniform (scalar loads), S reads coalesced.
__global__ __launch_bounds__(256) void buildl2_kernel(const float* __restrict__ S3c,
                                                      const float* __restrict__ S2c,
                                                      const float* __restrict__ S1c,
                                                      const int* __restrict__ ii1,
                                                      const float* __restrict__ iw1,
                                                      const int* __restrict__ ii2,
                                                      const float* __restrict__ iw2,
                                                      float* __restrict__ l2) {
  const int t = blockIdx.x * 256 + threadIdx.x;  // exact: B*M1*448
  const int bm = t / 448;
  const int c = t - bm * 448;
  const int b = bm >> 10, m = bm & (M1 - 1);
  const int* id1 = ii1 + (long)bm * 3;
  const float* w1 = iw1 + (long)bm * 3;
  float v;
  if (c < O3) {
    float v2[3];
#pragma unroll
    for (int k = 0; k < 3; ++k) {
      const int m2 = id1[k];
      const int* id2 = ii2 + ((long)b * M2 + m2) * 3;
      const float* w2 = iw2 + ((long)b * M2 + m2) * 3;
      v2[k] = __fadd_rn(
          __fadd_rn(__fmul_rn(S3c[((long)b * M3 + id2[0]) * O3 + c], w2[0]),
                    __fmul_rn(S3c[((long)b * M3 + id2[1]) * O3 + c], w2[1])),
          __fmul_rn(S3c[((long)b * M3 + id2[2]) * O3 + c], w2[2]));
    }
    v = __fadd_rn(__fadd_rn(__fmul_rn(v2[0], w1[0]), __fmul_rn(v2[1], w1[1])),
                  __fmul_rn(v2[2], w1[2]));
  } else if (c < 384) {
    const int cc = c - O3;
    v = __fadd_rn(
        __fadd_rn(__fmul_rn(S2c[((long)b * M2 + id1[0]) * O2 + cc], w1[0]),
                  __fmul_rn(S2c[((long)b * M2 + id1[1]) * O2 + cc], w1[1])),
        __fmul_rn(S2c[((long)b * M2 + id1[2]) * O2 + cc], w1[2]));
  } else {
    v = S1c[((long)bm) * O1 + (c - 384)];
  }
  l2[t] = v;
}

// ---------------- mlp: interp-to-l1 + 2-layer MLP + frame update -------------
// 4 wave-units/block; l2T point-major => col staging is 3 coalesced row reads;
// W1T[c][o] => coalesced weight loads, col[c] LDS-broadcast.
__global__ __launch_bounds__(256) void mlp_kernel(const float* __restrict__ l2,
                                                  const int* __restrict__ ii,
                                                  const float* __restrict__ iw,
                                                  const float* __restrict__ W1T,
                                                  const float* __restrict__ b1,
                                                  const float* __restrict__ W2,
                                                  const float* __restrict__ b2,
                                                  float* __restrict__ frame,
                                                  float* __restrict__ out, int td) {
  __shared__ float smem[4 * 512];
  const int lane = threadIdx.x & 63;
  const int wave = threadIdx.x >> 6;
  float* col = smem + (size_t)wave * 512;
  float* h = col + 448;
  const int u = blockIdx.x * 4 + wave;  // exact: B*N0 units
  const int b = u >> 11, n = u & (N0 - 1);
  const int* id = ii + (long)u * 3;
  const float* w = iw + (long)u * 3;
  const float w0 = w[0], w1 = w[1], w2v = w[2];
  const float* r0 = l2 + ((long)b * M1 + id[0]) * 448;
  const float* r1 = l2 + ((long)b * M1 + id[1]) * 448;
  const float* r2 = l2 + ((long)b * M1 + id[2]) * 448;
  for (int c = lane; c < 448; c += 64)
    col[c] = __fadd_rn(__fadd_rn(__fmul_rn(r0[c], w0), __fmul_rn(r1[c], w1)),
                       __fmul_rn(r2[c], w2v));
  __builtin_amdgcn_wave_barrier();
  float acc = b1[lane];
  for (int c = 0; c < 448; ++c) acc = fmaf(W1T[(long)c * 64 + lane], col[c], acc);
  h[lane] = fmaxf(acc, 0.0f);
  __builtin_amdgcn_wave_barrier();
  if (lane < 3) {
    const float* w2r = W2 + lane * 64;
    float acc2 = b2[lane];
    for (int c = 0; c < 64; ++c) acc2 = fmaf(w2r[c], h[c], acc2);
    const float nf = frame[(long)u * 3 + lane] + acc2;
    frame[(long)u * 3 + lane] = nf;
    out[(((long)b * 4 + td) * N0 + n) * 3 + lane] = nf;
  }
}

extern "C" void kernel_launch(void* const* d_in, const int* in_sizes, int n_in,
                              void* d_out, int out_size, void* d_ws, size_t ws_size,
                              hipStream_t stream) {
  const float* xyzs = (const float*)d_in[0];
  const float* enw[3] = {(const float*)d_in[1], (const float*)d_in[2], (const float*)d_in[3]};
  const float* dew[3] = {(const float*)d_in[4], (const float*)d_in[5], (const float*)d_in[6]};
  const float* mw1 = (const float*)d_in[7];
  const float* mb1 = (const float*)d_in[8];
  const float* mw2 = (const float*)d_in[9];
  const float* mb2 = (const float*)d_in[10];
  float* out = (float*)d_out;

  float* ws = (float*)d_ws;
  size_t off = 0;
  auto alloc = [&](size_t nn) { float* p = ws + off; off += nn; return p; };
  const long st1 = (long)B * M1 * 3;
  float* frame = alloc((size_t)B * N0 * 3);
  float* xyz1e = alloc((size_t)4 * st1);
  float* xyz1d[2] = {alloc((size_t)st1), alloc((size_t)st1)};
  float* z1 = alloc((size_t)st1);
  float* S1bf[2] = {alloc((size_t)B * O1 * M1), alloc((size_t)B * O1 * M1)};
  float* S2bf[2] = {alloc((size_t)B * O2 * M2), alloc((size_t)B * O2 * M2)};
  float* S3bf[2] = {alloc((size_t)B * O3 * M3), alloc((size_t)B * O3 * M3)};
  float* l2 = alloc((size_t)B * 448 * M1);
  float* iw0 = alloc((size_t)B * N0 * 3);
  int* ii0 = (int*)alloc((size_t)B * N0 * 3);
  float* iw1 = alloc((size_t)B * M1 * 3);
  int* ii1 = (int*)alloc((size_t)B * M1 * 3);
  float* iw2 = alloc((size_t)B * M2 * 3);
  int* ii2 = (int*)alloc((size_t)B * M2 * 3);
  float* wt = alloc((size_t)WT_TOT);

  hipMemsetAsync(z1, 0, (size_t)st1 * 4, stream);
  hipMemsetAsync(S1bf[1], 0, (size_t)B * O1 * M1 * 4, stream);
  hipMemsetAsync(S2bf[1], 0, (size_t)B * O2 * M2 * 4, stream);
  hipMemsetAsync(S3bf[1], 0, (size_t)B * O3 * M3 * 4, stream);

  double r;
  r = 4.0 + 1e-6;             const float r2c1 = (float)(r * r);
  r = 2.0 * 4.0 / 4.0 + 1e-6; const float r2q2 = (float)(r * r);
  r = 2.0 * 4.0 + 1e-6;       const float r2c2 = (float)(r * r);
  r = 4.0 * 4.0 / 4.0 + 1e-6; const float r2q3 = (float)(r * r);
  r = 3.0 * 4.0 + 1e-6;       const float r2c3 = (float)(r * r);

  transpose_w<<<dim3((WT_TOT + 255) / 256), 256, 0, stream>>>(
      enw[0], enw[1], enw[2], dew[0], dew[1], dew[2], mw1, wt);

  // encoder FPS (4 timesteps) + merged copyframe (y==4)
  fps8<2048, 1024><<<dim3(B, 5), 256, 0, stream>>>(xyzs, (long)LF * N0 * 3,
                                                   (long)N0 * 3, xyz1e, XS, st1,
                                                   xyzs, frame, 4);

  // t=4: frame == xyzs[:,3] bit-exactly => reuse encoder t=3's FPS result.
  const float* x1_of_t[LF] = {
      xyz1e + 0 * st1, xyz1e + 1 * st1, xyz1e + 2 * st1, xyz1e + 3 * st1,
      xyz1e + 3 * st1, xyz1d[0], xyz1d[1], xyz1d[0]};

  const float* wt1[2] = {wt + WT_E1, wt + WT_D1};
  const float* wt2[2] = {wt + WT_E2, wt + WT_D2};
  const float* wt3[2] = {wt + WT_E3, wt + WT_D3};

  auto launch_fused = [&](int t1, int t2, int t3, int tk) {
    FusedArgs a{};
    int nb = 0;
    if (t1 >= 0) {
      a.n1 = B * M1 / 4;
      a.c1_xc = x1_of_t[t1];
      a.c1_xp = (t1 == 0) ? z1 : x1_of_t[t1 - 1];
      a.c1_W = wt1[t1 >= 4];
      a.c1_Sp = S1bf[1 - (t1 & 1)];
      a.c1_Sc = S1bf[t1 & 1];
      nb += a.n1;
    }
    if (t2 >= 0) {
      a.n2 = B * M2 / 2;
      a.c2_xc = x1_of_t[t2];
      a.c2_xp = (t2 == 0) ? z1 : x1_of_t[t2 - 1];
      a.c2_W = wt2[t2 >= 4];
      a.c2_Sp = S2bf[1 - (t2 & 1)];
      a.c2_S1 = S1bf[t2 & 1];
      a.c2_Sc = S2bf[t2 & 1];
      nb += a.n2;
    }
    if (t3 >= 0) {
      a.n3 = B * M3;
      a.c3_xc = x1_of_t[t3];
      a.c3_xp = (t3 == 0) ? z1 : x1_of_t[t3 - 1];
      a.c3_W = wt3[t3 >= 4];
      a.c3_Sp = S3bf[1 - (t3 & 1)];
      a.c3_S2 = S2bf[t3 & 1];
      a.c3_Sc = S3bf[t3 & 1];
      nb += a.n3;
    }
    if (tk >= 0) {
      a.nk = B * (M2 + M1 + N0) / 256;  // 56
      a.k_xc = x1_of_t[tk];
      a.k_frame = frame;
      a.ii2 = ii2; a.ii1 = ii1; a.ii0 = ii0;
      a.iw2 = iw2; a.iw1 = iw1; a.iw0 = iw0;
      nb += a.nk;
    }
    a.r2c1 = r2c1; a.r2c2 = r2c2; a.r2q2 = r2q2; a.r2c3 = r2c3; a.r2q3 = r2q3;
    fused_cells<<<dim3((unsigned)nb), 256, 0, stream>>>(a);
  };

  auto tail = [&](int t) {
    buildl2_kernel<<<dim3(B * 448 * M1 / 256), 256, 0, stream>>>(
        S3bf[t & 1], S2bf[t & 1], S1bf[t & 1], ii1, iw1, ii2, iw2, l2);
    mlp_kernel<<<dim3(B * N0 / 4), 256, 0, stream>>>(
        l2, ii0, iw0, wt + WT_M1, mb1, mw2, mb2, frame, out, t - 4);
  };

  // encoder software pipeline + t=4 head (diagonal: independent tasks merged)
  launch_fused(0, -1, -1, -1);
  launch_fused(1, 0, -1, -1);
  launch_fused(2, 1, 0, -1);
  launch_fused(3, 2, 1, -1);
  launch_fused(4, 3, 2, 4);
  launch_fused(-1, 4, 3, -1);
  launch_fused(-1, -1, 4, -1);
  tail(4);

  for (int t = 5; t < LF; ++t) {
    fps8<2048, 1024><<<dim3(B, 1), 256, 0, stream>>>(frame, (long)N0 * 3, 0,
                                                     (float*)x1_of_t[t], XS, 0,
                                                     nullptr, nullptr, -1);
    launch_fused(t, -1, -1, t);
    launch_fused(-1, t, -1, -1);
    launch_fused(-1, -1, t, -1);
    tail(t);
  }
  (void)in_sizes; (void)n_in; (void)out_size; (void)ws_size;
}

// Round 12
// 3553.283 us; speedup vs baseline: 1.6394x; 1.0393x over previous
//
#include <hip/hip_runtime.h>

// ---------------- problem constants ----------------
static constexpr int B  = 4;
static constexpr int N0 = 2048;
static constexpr int LF = 8;
static constexpr int M1 = 1024, M2 = 512, M3 = 256;
static constexpr int O1 = 64, O2 = 128, O3 = 256;
static constexpr int NS1 = 12, NS2 = 8, NS3 = 4, NSQ = 4;
static constexpr int C1 = 67, C2 = 195, C3 = 387;
static constexpr int C41 = 68, C42 = 196, C43 = 388;  // padded to /4 (pad w=0, corr=0)
static constexpr long XS = 3 * (long)M1;  // xyz batch stride; L2/L3 = prefixes (r6)

// packed-weight pool offsets (floats): WP[c/4][o][4], zero-padded c
static constexpr int WP_E1 = 0;                       // 64*68   = 4352
static constexpr int WP_E2 = 4352;                    // 128*196 = 25088
static constexpr int WP_E3 = 29440;                   // 256*388 = 99328
static constexpr int WP_D1 = 128768;
static constexpr int WP_D2 = 133120;
static constexpr int WP_D3 = 158208;
static constexpr int WP_M1 = 257536;                  // 64*448  = 28672
static constexpr int WP_TOT = 286208;

__device__ __forceinline__ float sq3(float ax, float ay, float az,
                                     float bx, float by, float bz) {
  float dx = __fsub_rn(ax, bx), dy = __fsub_rn(ay, by), dz = __fsub_rn(az, bz);
  return __fadd_rn(__fadd_rn(__fmul_rn(dx, dx), __fmul_rn(dy, dy)),
                   __fmul_rn(dz, dz));
}

template <int CTRL>
__device__ __forceinline__ void dpp_max_step(unsigned& hi, unsigned& lo) {
  unsigned ohi = (unsigned)__builtin_amdgcn_update_dpp((int)hi, (int)hi, CTRL, 0xf, 0xf, false);
  unsigned olo = (unsigned)__builtin_amdgcn_update_dpp((int)lo, (int)lo, CTRL, 0xf, 0xf, false);
  bool take = (ohi > hi) || (ohi == hi && olo > lo);
  hi = take ? ohi : hi;
  lo = take ? olo : lo;
}

// elementwise 3-way weighted sum, numpy op order, per component (bit-exact)
__device__ __forceinline__ float4 wsum3(float4 a, float4 b, float4 c,
                                        float w0, float w1, float w2) {
  float4 r;
  r.x = __fadd_rn(__fadd_rn(__fmul_rn(a.x, w0), __fmul_rn(b.x, w1)), __fmul_rn(c.x, w2));
  r.y = __fadd_rn(__fadd_rn(__fmul_rn(a.y, w0), __fmul_rn(b.y, w1)), __fmul_rn(c.y, w2));
  r.z = __fadd_rn(__fadd_rn(__fmul_rn(a.z, w0), __fmul_rn(b.z, w1)), __fmul_rn(c.z, w2));
  r.w = __fadd_rn(__fadd_rn(__fmul_rn(a.w, w0), __fmul_rn(b.w, w1)), __fmul_rn(c.w, w2));
  return r;
}

// ---------------- weight pack: W[o][c] -> WP[c/4][o][4] (pool pre-zeroed) ----
__global__ __launch_bounds__(256) void pack_w(
    const float* __restrict__ e1, const float* __restrict__ e2,
    const float* __restrict__ e3, const float* __restrict__ d1,
    const float* __restrict__ d2, const float* __restrict__ d3,
    const float* __restrict__ m1, float* __restrict__ dst) {
  int t = blockIdx.x * 256 + threadIdx.x;
  const float* src; int C, O; long dof;
  if (t < 4288) { src = e1; C = C1; O = O1; dof = WP_E1; }
  else if (t < 29248) { src = e2; C = C2; O = O2; dof = WP_E2; t -= 4288; }
  else if (t < 128320) { src = e3; C = C3; O = O3; dof = WP_E3; t -= 29248; }
  else if (t < 132608) { src = d1; C = C1; O = O1; dof = WP_D1; t -= 128320; }
  else if (t < 157568) { src = d2; C = C2; O = O2; dof = WP_D2; t -= 132608; }
  else if (t < 256640) { src = d3; C = C3; O = O3; dof = WP_D3; t -= 157568; }
  else if (t < 285312) { src = m1; C = 448; O = 64; dof = WP_M1; t -= 256640; }
  else return;
  const int o = t / C, c = t - o * C;
  dst[dof + ((long)(c >> 2) * O + o) * 4 + (c & 3)] = src[t];
}

// ---------------- furthest point sampling (fps8, best measured r3-r11) -------
template <int N, int NPOINT>
__global__ __launch_bounds__(256, 1) void fps8(const float* __restrict__ pts,
                                               long s1, long s2,
                                               float* __restrict__ out,
                                               long o1, long o2,
                                               const float* __restrict__ cfsrc,
                                               float* __restrict__ cfdst,
                                               int copy_y) {
  if ((int)blockIdx.y == copy_y) {  // merged copyframe
    const int b = blockIdx.x;
    for (int e = threadIdx.x; e < N0 * 3; e += 256)
      cfdst[(long)b * N0 * 3 + e] = cfsrc[((long)b * LF + (LF / 2 - 1)) * N0 * 3 + e];
    return;
  }
  constexpr int K = N / 256;
  const float* p = pts + (long)blockIdx.x * s1 + (long)blockIdx.y * s2;
  float* outb = out + (long)blockIdx.x * o1 + (long)blockIdx.y * o2;
  const int tid = threadIdx.x;
  const int lane = tid & 63;
  const int wid = tid >> 6;
  __shared__ float4 sp[N];
  __shared__ float sel[NPOINT * 3];
  __shared__ unsigned long long wbest[2][4];
  float ppx[K], ppy[K], ppz[K], dist[K];
#pragma unroll
  for (int k = 0; k < K; ++k) {
    const int j = k * 256 + tid;
    const float x = p[3 * j + 0], y = p[3 * j + 1], z = p[3 * j + 2];
    ppx[k] = x; ppy[k] = y; ppz[k] = z;
    sp[j] = make_float4(x, y, z, 0.f);
    dist[k] = 1e10f;
  }
  __syncthreads();
  const float4 c0 = sp[0];
  float lx = c0.x, ly = c0.y, lz = c0.z;
  for (int i = 0; i < NPOINT; ++i) {
    if (tid == 0) {
      sel[3 * i + 0] = lx; sel[3 * i + 1] = ly; sel[3 * i + 2] = lz;
    }
    unsigned bhi = 0u;
    int bk = 0;
#pragma unroll
    for (int k = 0; k < K; ++k) {
      const float d = sq3(ppx[k], ppy[k], ppz[k], lx, ly, lz);
      const float dm = fminf(dist[k], d);
      dist[k] = dm;
      const unsigned h = __float_as_uint(dm);
      const bool take = h > bhi;  // strict > keeps smallest k (first occurrence)
      bhi = take ? h : bhi;
      bk = take ? k : bk;
    }
    unsigned blo = 2047u - (unsigned)(bk * 256 + tid);
    dpp_max_step<0x111>(bhi, blo);
    dpp_max_step<0x112>(bhi, blo);
    dpp_max_step<0x114>(bhi, blo);
    dpp_max_step<0x118>(bhi, blo);
    dpp_max_step<0x142>(bhi, blo);
    dpp_max_step<0x143>(bhi, blo);
    if (lane == 63)
      wbest[i & 1][wid] = ((unsigned long long)bhi << 32) | blo;
    __syncthreads();
    unsigned long long gk = 0ull;
#pragma unroll
    for (int w = 0; w < 4; ++w) {
      const unsigned long long e = wbest[i & 1][w];
      gk = (e > gk) ? e : gk;
    }
    const int gidx = 2047 - (int)(gk & 0x7FFull);
    const float4 c = sp[gidx];
    lx = c.x; ly = c.y; lz = c.z;
  }
  __syncthreads();
  for (int e = tid; e < NPOINT * 3; e += 256) outb[e] = sel[e];
}

// ---------------- wave-parallel ball query (first ns in-range, ascending) ----
template <int NS>
__device__ __forceinline__ void wave_bq(float qx, float qy, float qz,
                                        const float* __restrict__ src, int Ns,
                                        float r2, int* __restrict__ sidx, int lane) {
  int cnt = 0;
  for (int base = 0; base < Ns && cnt < NS; base += 64) {
    const int j = base + lane;
    bool in = false;
    if (j < Ns)
      in = sq3(qx, qy, qz, src[3 * j], src[3 * j + 1], src[3 * j + 2]) < r2;
    const unsigned long long mask = __ballot(in);
    const int pos = cnt + (int)__popcll(mask & ((1ull << lane) - 1ull));
    if (in && pos < NS) sidx[pos] = j;
    cnt += (int)__popcll(mask);
  }
  const int cc = cnt < NS ? cnt : NS;
  const int fill = (cc > 0) ? sidx[0] : 0;
  if (lane >= cc && lane < NS) sidx[lane] = fill;
}

// ---------------- fused multi-cell (+knn) dispatch ----------------
// Point-major S[b][m][ch]; packed weights WP[c/4][o][4] (float4 coalesced);
// corr rows padded to C4 => matmul inner = ds_read_b128 broadcasts. Pad terms
// are fma(0,0,acc) = bit-preserving. Per-output FMA order (c ascending) and
// all _rn chains identical to r11 => bit-exact.
struct FusedArgs {
  int n1, n2, n3, nk;
  const float *c1_xc, *c1_xp, *c1_W, *c1_Sp; float* c1_Sc;
  const float *c2_xc, *c2_xp, *c2_W, *c2_Sp, *c2_S1; float* c2_Sc;
  const float *c3_xc, *c3_xp, *c3_W, *c3_Sp, *c3_S2; float* c3_Sc;
  const float *k_xc, *k_frame;
  int *ii2, *ii1, *ii0;
  float *iw2, *iw1, *iw0;
  float r2c1, r2c2, r2q2, r2c3, r2q3;
};

__global__ __launch_bounds__(256) void fused_cells(FusedArgs a) {
  __shared__ __align__(16) float smem[3312];
  const int tid = threadIdx.x;
  const int lane = tid & 63;
  const int wave = tid >> 6;
  int bid = blockIdx.x;

  if (bid < a.n1) {  // -------- cell level-1 (4 wave-units/block) --------
    float* corr2 = smem + (size_t)wave * 828;  // [NS1][C41]=816 + 12 sidx
    int* sidx = (int*)(corr2 + 816);
    const int u = bid * 4 + wave;
    const int b = u >> 10, m = u & (M1 - 1);
    const float* p1 = a.c1_xc + (long)b * XS + 3 * m;
    const float p1x = p1[0], p1y = p1[1], p1z = p1[2];
    const float* p2b = a.c1_xp + (long)b * XS;
    wave_bq<NS1>(p1x, p1y, p1z, p2b, M1, a.r2c1, sidx, lane);
    __builtin_amdgcn_wave_barrier();
    for (int e = lane; e < NS1 * C41; e += 64) {
      const int s = e / C41, c = e - s * C41;
      const int j = sidx[s];
      float v;
      if (c < O1) {
        v = a.c1_Sp[((long)b * M1 + j) * O1 + c];
      } else if (c < C1) {
        const int d = c - O1;
        v = __fsub_rn(p2b[3 * j + d], (d == 0) ? p1x : ((d == 1) ? p1y : p1z));
      } else {
        v = 0.f;  // pad
      }
      corr2[e] = v;
    }
    __builtin_amdgcn_wave_barrier();
    const float4* wp4 = (const float4*)a.c1_W;
    float accs[NS1];
#pragma unroll
    for (int s = 0; s < NS1; ++s) accs[s] = 0.f;
    for (int q = 0; q < C41 / 4; ++q) {
      const float4 wv = wp4[(long)q * O1 + lane];
#pragma unroll
      for (int s = 0; s < NS1; ++s) {
        const float4 cv = *(const float4*)(corr2 + s * C41 + 4 * q);
        float acc = accs[s];
        acc = fmaf(wv.x, cv.x, acc);
        acc = fmaf(wv.y, cv.y, acc);
        acc = fmaf(wv.z, cv.z, acc);
        acc = fmaf(wv.w, cv.w, acc);
        accs[s] = acc;
      }
    }
    float best = accs[0];
#pragma unroll
    for (int s = 1; s < NS1; ++s) best = fmaxf(best, accs[s]);
    a.c1_Sc[((long)b * M1 + m) * O1 + lane] = best;
    return;
  }
  bid -= a.n1;

  if (bid < a.n2) {  // -------- cell level-2 (2 128-thr units/block) --------
    const int half = tid >> 7;
    const int ht = tid & 127;
    const int hw = (tid >> 6) & 1;
    float* base = smem + (size_t)half * 1644;
    float* corr2 = base;                 // [NS2][C42] = 1568
    int* sidx = (int*)(base + 1568);     // 8
    int* sfidx = (int*)(base + 1576);    // 4
    float* feat = base + 1580;           // 64
    const int u = bid * 2 + half;
    const int b = u >> 9, m = u & (M2 - 1);
    const float* p1 = a.c2_xc + (long)b * XS + 3 * m;
    const float p1x = p1[0], p1y = p1[1], p1z = p1[2];
    const float* p2b = a.c2_xp + (long)b * XS;
    if (hw == 0)
      wave_bq<NS2>(p1x, p1y, p1z, p2b, M2, a.r2c2, sidx, lane);
    else
      wave_bq<NSQ>(p1x, p1y, p1z, a.c2_xc + (long)b * XS, M1, a.r2q2, sfidx, lane);
    __syncthreads();
    if (ht < O1) {
      float bv = -3.0e38f;
#pragma unroll
      for (int s = 0; s < NSQ; ++s)
        bv = fmaxf(bv, a.c2_S1[((long)b * M1 + sfidx[s]) * O1 + ht]);
      feat[ht] = bv;
    }
    __syncthreads();
    for (int e = ht; e < NS2 * C42; e += 128) {
      const int s = e / C42, c = e - s * C42;
      const int j = sidx[s];
      float v;
      if (c < O2) {
        v = a.c2_Sp[((long)b * M2 + j) * O2 + c];
      } else if (c < O2 + O1) {
        v = feat[c - O2];
      } else if (c < C2) {
        const int d = c - O2 - O1;
        v = __fsub_rn(p2b[3 * j + d], (d == 0) ? p1x : ((d == 1) ? p1y : p1z));
      } else {
        v = 0.f;
      }
      corr2[e] = v;
    }
    __syncthreads();
    const float4* wp4 = (const float4*)a.c2_W;
    float accs[NS2];
#pragma unroll
    for (int s = 0; s < NS2; ++s) accs[s] = 0.f;
    for (int q = 0; q < C42 / 4; ++q) {
      const float4 wv = wp4[(long)q * O2 + ht];
#pragma unroll
      for (int s = 0; s < NS2; ++s) {
        const float4 cv = *(const float4*)(corr2 + s * C42 + 4 * q);
        float acc = accs[s];
        acc = fmaf(wv.x, cv.x, acc);
        acc = fmaf(wv.y, cv.y, acc);
        acc = fmaf(wv.z, cv.z, acc);
        acc = fmaf(wv.w, cv.w, acc);
        accs[s] = acc;
      }
    }
    float best = accs[0];
#pragma unroll
    for (int s = 1; s < NS2; ++s) best = fmaxf(best, accs[s]);
    a.c2_Sc[((long)b * M2 + m) * O2 + ht] = best;
    return;
  }
  bid -= a.n2;

  if (bid < a.n3) {  // -------- cell level-3 (1 unit/block, 256 thr) --------
    float* corr2 = smem;                 // [NS3][C43] = 1552
    int* sidx = (int*)(smem + 1552);
    int* sfidx = (int*)(smem + 1556);
    float* feat = smem + 1560;           // 128
    const int b = bid >> 8, m = bid & (M3 - 1);
    const float* p1 = a.c3_xc + (long)b * XS + 3 * m;
    const float p1x = p1[0], p1y = p1[1], p1z = p1[2];
    const float* p2b = a.c3_xp + (long)b * XS;
    if (wave == 0)
      wave_bq<NS3>(p1x, p1y, p1z, p2b, M3, a.r2c3, sidx, lane);
    else if (wave == 1)
      wave_bq<NSQ>(p1x, p1y, p1z, a.c3_xc + (long)b * XS, M2, a.r2q3, sfidx, lane);
    __syncthreads();
    if (tid < O2) {
      float bv = -3.0e38f;
#pragma unroll
      for (int s = 0; s < NSQ; ++s)
        bv = fmaxf(bv, a.c3_S2[((long)b * M2 + sfidx[s]) * O2 + tid]);
      feat[tid] = bv;
    }
    __syncthreads();
    for (int e = tid; e < NS3 * C43; e += 256) {
      const int s = e / C43, c = e - s * C43;
      const int j = sidx[s];
      float v;
      if (c < O3) {
        v = a.c3_Sp[((long)b * M3 + j) * O3 + c];
      } else if (c < O3 + O2) {
        v = feat[c - O3];
      } else if (c < C3) {
        const int d = c - O3 - O2;
        v = __fsub_rn(p2b[3 * j + d], (d == 0) ? p1x : ((d == 1) ? p1y : p1z));
      } else {
        v = 0.f;
      }
      corr2[e] = v;
    }
    __syncthreads();
    const float4* wp4 = (const float4*)a.c3_W;
    float accs[NS3];
#pragma unroll
    for (int s = 0; s < NS3; ++s) accs[s] = 0.f;
    for (int q = 0; q < C43 / 4; ++q) {
      const float4 wv = wp4[(long)q * O3 + tid];
#pragma unroll
      for (int s = 0; s < NS3; ++s) {
        const float4 cv = *(const float4*)(corr2 + s * C43 + 4 * q);
        float acc = accs[s];
        acc = fmaf(wv.x, cv.x, acc);
        acc = fmaf(wv.y, cv.y, acc);
        acc = fmaf(wv.z, cv.z, acc);
        acc = fmaf(wv.w, cv.w, acc);
        accs[s] = acc;
      }
    }
    float best = accs[0];
#pragma unroll
    for (int s = 1; s < NS3; ++s) best = fmaxf(best, accs[s]);
    a.c3_Sc[((long)b * M3 + m) * O3 + tid] = best;
    return;
  }
  bid -= a.n3;

  {  // -------- knn: all three interp levels (56 blocks exact) --------
    int t = bid * 256 + tid;
    const float* unk; long ustr; int Mu, Mk; int* oi; float* ow;
    if (t < B * M2) {
      unk = a.k_xc; ustr = XS; Mu = M2; Mk = M3; oi = a.ii2; ow = a.iw2;
    } else if (t < B * (M2 + M1)) {
      t -= B * M2;
      unk = a.k_xc; ustr = XS; Mu = M1; Mk = M2; oi = a.ii1; ow = a.iw1;
    } else {
      t -= B * (M2 + M1);
      unk = a.k_frame; ustr = 3L * N0; Mu = N0; Mk = M1; oi = a.ii0; ow = a.iw0;
    }
    const int b = t / Mu, m = t - b * Mu;
    const float* q = unk + (long)b * ustr + (long)m * 3;
    const float qx = q[0], qy = q[1], qz = q[2];
    const float* s = a.k_xc + (long)b * XS;
    float d0 = 3e38f, d1 = 3e38f, d2v = 3e38f;
    int i0 = 0, i1 = 0, i2 = 0;
    for (int j = 0; j < Mk; ++j) {
      float dd = sq3(qx, qy, qz, s[3 * j], s[3 * j + 1], s[3 * j + 2]);
      if (dd < d0) {
        d2v = d1; i2 = i1; d1 = d0; i1 = i0; d0 = dd; i0 = j;
      } else if (dd < d1) {
        d2v = d1; i2 = i1; d1 = dd; i1 = j;
      } else if (dd < d2v) {
        d2v = dd; i2 = j;
      }
    }
    float r0 = 1.0f / __fadd_rn(d0, 1e-8f);
    float r1 = 1.0f / __fadd_rn(d1, 1e-8f);
    float r2 = 1.0f / __fadd_rn(d2v, 1e-8f);
    float sum = __fadd_rn(__fadd_rn(r0, r1), r2);
    ow[t * 3 + 0] = r0 / sum;
    ow[t * 3 + 1] = r1 / sum;
    ow[t * 3 + 2] = r2 / sum;
    oi[t * 3 + 0] = i0;
    oi[t * 3 + 1] = i1;
    oi[t * 3 + 2] = i2;
  }
}

// ---------------- buildl2 (float4 per thread, fully coalesced) ----------------
// One thread = 4 consecutive channels of one (b,m). Region splits at 256/384
// are 4-aligned so chunks never straddle. Per-element op chains identical.
__global__ __launch_bounds__(256) void buildl2_kernel(const float* __restrict__ S3c,
                                                      const float* __restrict__ S2c,
                                                      const float* __restrict__ S1c,
                                                      const int* __restrict__ ii1,
                                                      const float* __restrict__ iw1,
                                                      const int* __restrict__ ii2,
                                                      const float* __restrict__ iw2,
                                                      float* __restrict__ l2) {
  const int t = blockIdx.x * 256 + threadIdx.x;  // exact: B*M1*112
  const int bm = t / 112;
  const int c0 = (t - bm * 112) * 4;
  const int b = bm >> 10;
  const int* id1 = ii1 + (long)bm * 3;
  const float* w1 = iw1 + (long)bm * 3;
  float4 v;
  if (c0 < O3) {
    float4 v2[3];
#pragma unroll
    for (int k = 0; k < 3; ++k) {
      const int m2 = id1[k];
      const int* id2 = ii2 + ((long)b * M2 + m2) * 3;
      const float* w2 = iw2 + ((long)b * M2 + m2) * 3;
      const float4 s0 = *(const float4*)(S3c + ((long)b * M3 + id2[0]) * O3 + c0);
      const float4 s1 = *(const float4*)(S3c + ((long)b * M3 + id2[1]) * O3 + c0);
      const float4 s2 = *(const float4*)(S3c + ((long)b * M3 + id2[2]) * O3 + c0);
      v2[k] = wsum3(s0, s1, s2, w2[0], w2[1], w2[2]);
    }
    v = wsum3(v2[0], v2[1], v2[2], w1[0], w1[1], w1[2]);
  } else if (c0 < 384) {
    const int cc = c0 - O3;
    const float4 s0 = *(const float4*)(S2c + ((long)b * M2 + id1[0]) * O2 + cc);
    const float4 s1 = *(const float4*)(S2c + ((long)b * M2 + id1[1]) * O2 + cc);
    const float4 s2 = *(const float4*)(S2c + ((long)b * M2 + id1[2]) * O2 + cc);
    v = wsum3(s0, s1, s2, w1[0], w1[1], w1[2]);
  } else {
    v = *(const float4*)(S1c + (long)bm * O1 + (c0 - 384));
  }
  *(float4*)(l2 + (long)bm * 448 + c0) = v;
}

// ---------------- mlp: interp-to-l1 + 2-layer MLP + frame update -------------
// 4 wave-units/block; float4 col staging (global float4 gathers) and float4
// packed-W1 loads; col read back as b128 broadcasts.
__global__ __launch_bounds__(256) void mlp_kernel(const float* __restrict__ l2,
                                                  const int* __restrict__ ii,
                                                  const float* __restrict__ iw,
                                                  const float* __restrict__ W1P,
                                                  const float* __restrict__ b1,
                                                  const float* __restrict__ W2,
                                                  const float* __restrict__ b2,
                                                  float* __restrict__ frame,
                                                  float* __restrict__ out, int td) {
  __shared__ __align__(16) float smem[4 * 512];
  const int lane = threadIdx.x & 63;
  const int wave = threadIdx.x >> 6;
  float* col = smem + (size_t)wave * 512;
  float* h = col + 448;
  const int u = blockIdx.x * 4 + wave;  // exact: B*N0 units
  const int b = u >> 11, n = u & (N0 - 1);
  const int* id = ii + (long)u * 3;
  const float* w = iw + (long)u * 3;
  const float w0 = w[0], w1 = w[1], w2v = w[2];
  const float4* r0 = (const float4*)(l2 + ((long)b * M1 + id[0]) * 448);
  const float4* r1 = (const float4*)(l2 + ((long)b * M1 + id[1]) * 448);
  const float4* r2 = (const float4*)(l2 + ((long)b * M1 + id[2]) * 448);
  float4* col4 = (float4*)col;
  for (int q = lane; q < 112; q += 64)
    col4[q] = wsum3(r0[q], r1[q], r2[q], w0, w1, w2v);
  __builtin_amdgcn_wave_barrier();
  const float4* wp4 = (const float4*)W1P;
  float acc = b1[lane];
  for (int q = 0; q < 112; ++q) {
    const float4 wv = wp4[(long)q * 64 + lane];
    const float4 cv = col4[q];
    acc = fmaf(wv.x, cv.x, acc);
    acc = fmaf(wv.y, cv.y, acc);
    acc = fmaf(wv.z, cv.z, acc);
    acc = fmaf(wv.w, cv.w, acc);
  }
  h[lane] = fmaxf(acc, 0.0f);
  __builtin_amdgcn_wave_barrier();
  if (lane < 3) {
    const float* w2r = W2 + lane * 64;
    float acc2 = b2[lane];
    for (int c = 0; c < 64; ++c) acc2 = fmaf(w2r[c], h[c], acc2);
    const float nf = frame[(long)u * 3 + lane] + acc2;
    frame[(long)u * 3 + lane] = nf;
    out[(((long)b * 4 + td) * N0 + n) * 3 + lane] = nf;
  }
}

extern "C" void kernel_launch(void* const* d_in, const int* in_sizes, int n_in,
                              void* d_out, int out_size, void* d_ws, size_t ws_size,
                              hipStream_t stream) {
  const float* xyzs = (const float*)d_in[0];
  const float* enw[3] = {(const float*)d_in[1], (const float*)d_in[2], (const float*)d_in[3]};
  const float* dew[3] = {(const float*)d_in[4], (const float*)d_in[5], (const float*)d_in[6]};
  const float* mw1 = (const float*)d_in[7];
  const float* mb1 = (const float*)d_in[8];
  const float* mw2 = (const float*)d_in[9];
  const float* mb2 = (const float*)d_in[10];
  float* out = (float*)d_out;

  float* ws = (float*)d_ws;
  size_t off = 0;
  auto alloc = [&](size_t nn) { float* p = ws + off; off += nn; return p; };
  const long st1 = (long)B * M1 * 3;
  float* frame = alloc((size_t)B * N0 * 3);
  float* xyz1e = alloc((size_t)4 * st1);
  float* xyz1d[2] = {alloc((size_t)st1), alloc((size_t)st1)};
  float* z1 = alloc((size_t)st1);
  float* S1bf[2] = {alloc((size_t)B * O1 * M1), alloc((size_t)B * O1 * M1)};
  float* S2bf[2] = {alloc((size_t)B * O2 * M2), alloc((size_t)B * O2 * M2)};
  float* S3bf[2] = {alloc((size_t)B * O3 * M3), alloc((size_t)B * O3 * M3)};
  float* l2 = alloc((size_t)B * 448 * M1);
  float* iw0 = alloc((size_t)B * N0 * 3);
  int* ii0 = (int*)alloc((size_t)B * N0 * 3);
  float* iw1 = alloc((size_t)B * M1 * 3);
  int* ii1 = (int*)alloc((size_t)B * M1 * 3);
  float* iw2 = alloc((size_t)B * M2 * 3);
  int* ii2 = (int*)alloc((size_t)B * M2 * 3);
  float* wt = alloc((size_t)WP_TOT);

  hipMemsetAsync(z1, 0, (size_t)st1 * 4, stream);
  hipMemsetAsync(S1bf[1], 0, (size_t)B * O1 * M1 * 4, stream);
  hipMemsetAsync(S2bf[1], 0, (size_t)B * O2 * M2 * 4, stream);
  hipMemsetAsync(S3bf[1], 0, (size_t)B * O3 * M3 * 4, stream);
  hipMemsetAsync(wt, 0, (size_t)WP_TOT * 4, stream);  // pad weights must be 0

  double r;
  r = 4.0 + 1e-6;             const float r2c1 = (float)(r * r);
  r = 2.0 * 4.0 / 4.0 + 1e-6; const float r2q2 = (float)(r * r);
  r = 2.0 * 4.0 + 1e-6;       const float r2c2 = (float)(r * r);
  r = 4.0 * 4.0 / 4.0 + 1e-6; const float r2q3 = (float)(r * r);
  r = 3.0 * 4.0 + 1e-6;       const float r2c3 = (float)(r * r);

  pack_w<<<dim3((285312 + 255) / 256), 256, 0, stream>>>(
      enw[0], enw[1], enw[2], dew[0], dew[1], dew[2], mw1, wt);

  // encoder FPS (4 timesteps) + merged copyframe (y==4)
  fps8<2048, 1024><<<dim3(B, 5), 256, 0, stream>>>(xyzs, (long)LF * N0 * 3,
                                                   (long)N0 * 3, xyz1e, XS, st1,
                                                   xyzs, frame, 4);

  // t=4: frame == xyzs[:,3] bit-exactly => reuse encoder t=3's FPS result.
  const float* x1_of_t[LF] = {
      xyz1e + 0 * st1, xyz1e + 1 * st1, xyz1e + 2 * st1, xyz1e + 3 * st1,
      xyz1e + 3 * st1, xyz1d[0], xyz1d[1], xyz1d[0]};

  const float* wp1[2] = {wt + WP_E1, wt + WP_D1};
  const float* wp2[2] = {wt + WP_E2, wt + WP_D2};
  const float* wp3[2] = {wt + WP_E3, wt + WP_D3};

  auto launch_fused = [&](int t1, int t2, int t3, int tk) {
    FusedArgs a{};
    int nb = 0;
    if (t1 >= 0) {
      a.n1 = B * M1 / 4;
      a.c1_xc = x1_of_t[t1];
      a.c1_xp = (t1 == 0) ? z1 : x1_of_t[t1 - 1];
      a.c1_W = wp1[t1 >= 4];
      a.c1_Sp = S1bf[1 - (t1 & 1)];
      a.c1_Sc = S1bf[t1 & 1];
      nb += a.n1;
    }
    if (t2 >= 0) {
      a.n2 = B * M2 / 2;
      a.c2_xc = x1_of_t[t2];
      a.c2_xp = (t2 == 0) ? z1 : x1_of_t[t2 - 1];
      a.c2_W = wp2[t2 >= 4];
      a.c2_Sp = S2bf[1 - (t2 & 1)];
      a.c2_S1 = S1bf[t2 & 1];
      a.c2_Sc = S2bf[t2 & 1];
      nb += a.n2;
    }
    if (t3 >= 0) {
      a.n3 = B * M3;
      a.c3_xc = x1_of_t[t3];
      a.c3_xp = (t3 == 0) ? z1 : x1_of_t[t3 - 1];
      a.c3_W = wp3[t3 >= 4];
      a.c3_Sp = S3bf[1 - (t3 & 1)];
      a.c3_S2 = S2bf[t3 & 1];
      a.c3_Sc = S3bf[t3 & 1];
      nb += a.n3;
    }
    if (tk >= 0) {
      a.nk = B * (M2 + M1 + N0) / 256;  // 56
      a.k_xc = x1_of_t[tk];
      a.k_frame = frame;
      a.ii2 = ii2; a.ii1 = ii1; a.ii0 = ii0;
      a.iw2 = iw2; a.iw1 = iw1; a.iw0 = iw0;
      nb += a.nk;
    }
    a.r2c1 = r2c1; a.r2c2 = r2c2; a.r2q2 = r2q2; a.r2c3 = r2c3; a.r2q3 = r2q3;
    fused_cells<<<dim3((unsigned)nb), 256, 0, stream>>>(a);
  };

  auto tail = [&](int t) {
    buildl2_kernel<<<dim3(B * M1 * 112 / 256), 256, 0, stream>>>(
        S3bf[t & 1], S2bf[t & 1], S1bf[t & 1], ii1, iw1, ii2, iw2, l2);
    mlp_kernel<<<dim3(B * N0 / 4), 256, 0, stream>>>(
        l2, ii0, iw0, wt + WP_M1, mb1, mw2, mb2, frame, out, t - 4);
  };

  // encoder software pipeline + t=4 head (diagonal: independent tasks merged)
  launch_fused(0, -1, -1, -1);
  launch_fused(1, 0, -1, -1);
  launch_fused(2, 1, 0, -1);
  launch_fused(3, 2, 1, -1);
  launch_fused(4, 3, 2, 4);
  launch_fused(-1, 4, 3, -1);
  launch_fused(-1, -1, 4, -1);
  tail(4);

  for (int t = 5; t < LF; ++t) {
    fps8<2048, 1024><<<dim3(B, 1), 256, 0, stream>>>(frame, (long)N0 * 3, 0,
                                                     (float*)x1_of_t[t], XS, 0,
                                                     nullptr, nullptr, -1);
    launch_fused(t, -1, -1, t);
    launch_fused(-1, t, -1, -1);
    launch_fused(-1, -1, t, -1);
    tail(t);
  }
  (void)in_sizes; (void)n_in; (void)out_size; (void)ws_size;
}

// Round 13
// 2768.120 us; speedup vs baseline: 2.1044x; 1.2836x over previous
//
#include <hip/hip_runtime.h>

// ---------------- problem constants ----------------
static constexpr int B  = 4;
static constexpr int N0 = 2048;
static constexpr int LF = 8;
static constexpr int M1 = 1024, M2 = 512, M3 = 256;
static constexpr int O1 = 64, O2 = 128, O3 = 256;
static constexpr int NS1 = 12, NS2 = 8, NS3 = 4, NSQ = 4;
static constexpr int C1 = 67, C2 = 195, C3 = 387;
static constexpr int C41 = 68, C42 = 196, C43 = 388;  // padded to /4 (pad w=0, corr=0)
static constexpr long XS = 3 * (long)M1;  // xyz batch stride; L2/L3 = prefixes (r6)

// packed-weight pool offsets (floats): WP[c/4][o][4], zero-padded c
static constexpr int WP_E1 = 0;
static constexpr int WP_E2 = 4352;
static constexpr int WP_E3 = 29440;
static constexpr int WP_D1 = 128768;
static constexpr int WP_D2 = 133120;
static constexpr int WP_D3 = 158208;
static constexpr int WP_M1 = 257536;
static constexpr int WP_TOT = 286208;

__device__ __forceinline__ float sq3(float ax, float ay, float az,
                                     float bx, float by, float bz) {
  float dx = __fsub_rn(ax, bx), dy = __fsub_rn(ay, by), dz = __fsub_rn(az, bz);
  return __fadd_rn(__fadd_rn(__fmul_rn(dx, dx), __fmul_rn(dy, dy)),
                   __fmul_rn(dz, dz));
}

template <int CTRL>
__device__ __forceinline__ int dpp_i(int v) {
  return __builtin_amdgcn_update_dpp(v, v, CTRL, 0xf, 0xf, false);
}
// f32 max step (1 combine op; self-fallback idempotent). Valid for dm >= 0.
template <int CTRL>
__device__ __forceinline__ float dpp_maxf(float m) {
  const float o = __uint_as_float((unsigned)dpp_i<CTRL>((int)__float_as_uint(m)));
  return fmaxf(m, o);
}
// u32 min step
template <int CTRL>
__device__ __forceinline__ unsigned dpp_minu(unsigned v) {
  const unsigned o = (unsigned)dpp_i<CTRL>((int)v);
  return o < v ? o : v;
}
// u64 (hi,lo) min step — for knn (d_bits, j) lexicographic extraction
template <int CTRL>
__device__ __forceinline__ void dpp_min64_step(unsigned& hi, unsigned& lo) {
  const unsigned ohi = (unsigned)dpp_i<CTRL>((int)hi);
  const unsigned olo = (unsigned)dpp_i<CTRL>((int)lo);
  const bool take = (ohi < hi) || (ohi == hi && olo < lo);
  hi = take ? ohi : hi;
  lo = take ? olo : lo;
}

// elementwise 3-way weighted sum, numpy op order, per component (bit-exact)
__device__ __forceinline__ float4 wsum3(float4 a, float4 b, float4 c,
                                        float w0, float w1, float w2) {
  float4 r;
  r.x = __fadd_rn(__fadd_rn(__fmul_rn(a.x, w0), __fmul_rn(b.x, w1)), __fmul_rn(c.x, w2));
  r.y = __fadd_rn(__fadd_rn(__fmul_rn(a.y, w0), __fmul_rn(b.y, w1)), __fmul_rn(c.y, w2));
  r.z = __fadd_rn(__fadd_rn(__fmul_rn(a.z, w0), __fmul_rn(b.z, w1)), __fmul_rn(c.z, w2));
  r.w = __fadd_rn(__fadd_rn(__fmul_rn(a.w, w0), __fmul_rn(b.w, w1)), __fmul_rn(c.w, w2));
  return r;
}

// ---------------- weight pack: W[o][c] -> WP[c/4][o][4] (pool pre-zeroed) ----
__global__ __launch_bounds__(256) void pack_w(
    const float* __restrict__ e1, const float* __restrict__ e2,
    const float* __restrict__ e3, const float* __restrict__ d1,
    const float* __restrict__ d2, const float* __restrict__ d3,
    const float* __restrict__ m1, float* __restrict__ dst) {
  int t = blockIdx.x * 256 + threadIdx.x;
  const float* src; int C, O; long dof;
  if (t < 4288) { src = e1; C = C1; O = O1; dof = WP_E1; }
  else if (t < 29248) { src = e2; C = C2; O = O2; dof = WP_E2; t -= 4288; }
  else if (t < 128320) { src = e3; C = C3; O = O3; dof = WP_E3; t -= 29248; }
  else if (t < 132608) { src = d1; C = C1; O = O1; dof = WP_D1; t -= 128320; }
  else if (t < 157568) { src = d2; C = C2; O = O2; dof = WP_D2; t -= 132608; }
  else if (t < 256640) { src = d3; C = C3; O = O3; dof = WP_D3; t -= 157568; }
  else if (t < 285312) { src = m1; C = 448; O = 64; dof = WP_M1; t -= 256640; }
  else return;
  const int o = t / C, c = t - o * C;
  dst[dof + ((long)(c >> 2) * O + o) * 4 + (c & 3)] = src[t];
}

// ---------------- furthest point sampling (fps8 + split reduce) --------------
// Winner = (max dist, min index) — identical to the old u64-key max, computed
// as: 6x v_max_f32 DPP (dist, >=0 so float order == bit order) -> wmax; then
// candidates (bdm==wmax) reduce j via 6x v_min_u32 DPP. Tie-break matches
// jnp.argmax first-occurrence bit-exactly.
template <int N, int NPOINT>
__global__ __launch_bounds__(256, 1) void fps8(const float* __restrict__ pts,
                                               long s1, long s2,
                                               float* __restrict__ out,
                                               long o1, long o2,
                                               const float* __restrict__ cfsrc,
                                               float* __restrict__ cfdst,
                                               int copy_y) {
  if ((int)blockIdx.y == copy_y) {  // merged copyframe
    const int b = blockIdx.x;
    for (int e = threadIdx.x; e < N0 * 3; e += 256)
      cfdst[(long)b * N0 * 3 + e] = cfsrc[((long)b * LF + (LF / 2 - 1)) * N0 * 3 + e];
    return;
  }
  constexpr int K = N / 256;
  const float* p = pts + (long)blockIdx.x * s1 + (long)blockIdx.y * s2;
  float* outb = out + (long)blockIdx.x * o1 + (long)blockIdx.y * o2;
  const int tid = threadIdx.x;
  const int lane = tid & 63;
  const int wid = tid >> 6;
  __shared__ float4 sp[N];
  __shared__ float sel[NPOINT * 3];
  __shared__ unsigned long long wbest[2][4];
  float ppx[K], ppy[K], ppz[K], dist[K];
#pragma unroll
  for (int k = 0; k < K; ++k) {
    const int j = k * 256 + tid;
    const float x = p[3 * j + 0], y = p[3 * j + 1], z = p[3 * j + 2];
    ppx[k] = x; ppy[k] = y; ppz[k] = z;
    sp[j] = make_float4(x, y, z, 0.f);
    dist[k] = 1e10f;
  }
  __syncthreads();
  const float4 c0 = sp[0];
  float lx = c0.x, ly = c0.y, lz = c0.z;
  for (int i = 0; i < NPOINT; ++i) {
    if (tid == 0) {
      sel[3 * i + 0] = lx; sel[3 * i + 1] = ly; sel[3 * i + 2] = lz;
    }
    float bdm = 0.f;
    int bk = 0;
#pragma unroll
    for (int k = 0; k < K; ++k) {
      const float d = sq3(ppx[k], ppy[k], ppz[k], lx, ly, lz);
      const float dm = fminf(dist[k], d);
      dist[k] = dm;
      const bool take = dm > bdm;  // strict > keeps smallest k (first occurrence)
      bdm = take ? dm : bdm;
      bk = take ? k : bk;
    }
    // wave max of dist (single-op DPP steps)
    float mx = bdm;
    mx = dpp_maxf<0x111>(mx);
    mx = dpp_maxf<0x112>(mx);
    mx = dpp_maxf<0x114>(mx);
    mx = dpp_maxf<0x118>(mx);
    mx = dpp_maxf<0x142>(mx);
    mx = dpp_maxf<0x143>(mx);
    const float wmax = __uint_as_float(
        (unsigned)__builtin_amdgcn_readlane((int)__float_as_uint(mx), 63));
    // min index among dist-ties
    unsigned cand = (bdm == wmax) ? (unsigned)((bk << 8) + tid) : 0xFFFFFFFFu;
    cand = dpp_minu<0x111>(cand);
    cand = dpp_minu<0x112>(cand);
    cand = dpp_minu<0x114>(cand);
    cand = dpp_minu<0x118>(cand);
    cand = dpp_minu<0x142>(cand);
    cand = dpp_minu<0x143>(cand);
    const unsigned minj = (unsigned)__builtin_amdgcn_readlane((int)cand, 63);
    if (lane == 63)
      wbest[i & 1][wid] =
          ((unsigned long long)__float_as_uint(wmax) << 32) | (2047u - minj);
    __syncthreads();
    unsigned long long gk = 0ull;
#pragma unroll
    for (int w = 0; w < 4; ++w) {
      const unsigned long long e = wbest[i & 1][w];
      gk = (e > gk) ? e : gk;
    }
    const int gidx = 2047 - (int)(gk & 0x7FFull);
    const float4 c = sp[gidx];
    lx = c.x; ly = c.y; lz = c.z;
  }
  __syncthreads();
  for (int e = tid; e < NPOINT * 3; e += 256) outb[e] = sel[e];
}

// ---------------- wave-parallel ball query (first ns in-range, ascending) ----
template <int NS>
__device__ __forceinline__ void wave_bq(float qx, float qy, float qz,
                                        const float* __restrict__ src, int Ns,
                                        float r2, int* __restrict__ sidx, int lane) {
  int cnt = 0;
  for (int base = 0; base < Ns && cnt < NS; base += 64) {
    const int j = base + lane;
    bool in = false;
    if (j < Ns)
      in = sq3(qx, qy, qz, src[3 * j], src[3 * j + 1], src[3 * j + 2]) < r2;
    const unsigned long long mask = __ballot(in);
    const int pos = cnt + (int)__popcll(mask & ((1ull << lane) - 1ull));
    if (in && pos < NS) sidx[pos] = j;
    cnt += (int)__popcll(mask);
  }
  const int cc = cnt < NS ? cnt : NS;
  const int fill = (cc > 0) ? sidx[0] : 0;
  if (lane >= cc && lane < NS) sidx[lane] = fill;
}

// ---------------- fused multi-cell (+knn) dispatch ----------------
// Point-major S[b][m][ch]; packed weights WP[c/4][o][4]; corr rows padded to
// C4 (pad fma(0,0,acc) bit-preserving). knn is now WAVE-PER-QUERY (r12 profile:
// 56-block knn serialized ~37us on 56 CUs): each lane scans Mk/64 points with
// a sorted local top-3 of u64 (d_bits<<32|j) keys (strict-< insertion == stable
// lax.top_k (d,j) order), then 3 rounds of 6-step u64-min DPP extraction.
struct FusedArgs {
  int n1, n2, n3, nk;
  const float *c1_xc, *c1_xp, *c1_W, *c1_Sp; float* c1_Sc;
  const float *c2_xc, *c2_xp, *c2_W, *c2_Sp, *c2_S1; float* c2_Sc;
  const float *c3_xc, *c3_xp, *c3_W, *c3_Sp, *c3_S2; float* c3_Sc;
  const float *k_xc, *k_frame;
  int *ii2, *ii1, *ii0;
  float *iw2, *iw1, *iw0;
  float r2c1, r2c2, r2q2, r2c3, r2q3;
};

__global__ __launch_bounds__(256) void fused_cells(FusedArgs a) {
  __shared__ __align__(16) float smem[3312];
  const int tid = threadIdx.x;
  const int lane = tid & 63;
  const int wave = tid >> 6;
  int bid = blockIdx.x;

  if (bid < a.n1) {  // -------- cell level-1 (4 wave-units/block) --------
    float* corr2 = smem + (size_t)wave * 828;  // [NS1][C41]=816 + 12 sidx
    int* sidx = (int*)(corr2 + 816);
    const int u = bid * 4 + wave;
    const int b = u >> 10, m = u & (M1 - 1);
    const float* p1 = a.c1_xc + (long)b * XS + 3 * m;
    const float p1x = p1[0], p1y = p1[1], p1z = p1[2];
    const float* p2b = a.c1_xp + (long)b * XS;
    wave_bq<NS1>(p1x, p1y, p1z, p2b, M1, a.r2c1, sidx, lane);
    __builtin_amdgcn_wave_barrier();
    for (int e = lane; e < NS1 * C41; e += 64) {
      const int s = e / C41, c = e - s * C41;
      const int j = sidx[s];
      float v;
      if (c < O1) {
        v = a.c1_Sp[((long)b * M1 + j) * O1 + c];
      } else if (c < C1) {
        const int d = c - O1;
        v = __fsub_rn(p2b[3 * j + d], (d == 0) ? p1x : ((d == 1) ? p1y : p1z));
      } else {
        v = 0.f;  // pad
      }
      corr2[e] = v;
    }
    __builtin_amdgcn_wave_barrier();
    const float4* wp4 = (const float4*)a.c1_W;
    float accs[NS1];
#pragma unroll
    for (int s = 0; s < NS1; ++s) accs[s] = 0.f;
    for (int q = 0; q < C41 / 4; ++q) {
      const float4 wv = wp4[(long)q * O1 + lane];
#pragma unroll
      for (int s = 0; s < NS1; ++s) {
        const float4 cv = *(const float4*)(corr2 + s * C41 + 4 * q);
        float acc = accs[s];
        acc = fmaf(wv.x, cv.x, acc);
        acc = fmaf(wv.y, cv.y, acc);
        acc = fmaf(wv.z, cv.z, acc);
        acc = fmaf(wv.w, cv.w, acc);
        accs[s] = acc;
      }
    }
    float best = accs[0];
#pragma unroll
    for (int s = 1; s < NS1; ++s) best = fmaxf(best, accs[s]);
    a.c1_Sc[((long)b * M1 + m) * O1 + lane] = best;
    return;
  }
  bid -= a.n1;

  if (bid < a.n2) {  // -------- cell level-2 (2 128-thr units/block) --------
    const int half = tid >> 7;
    const int ht = tid & 127;
    const int hw = (tid >> 6) & 1;
    float* base = smem + (size_t)half * 1644;
    float* corr2 = base;                 // [NS2][C42] = 1568
    int* sidx = (int*)(base + 1568);     // 8
    int* sfidx = (int*)(base + 1576);    // 4
    float* feat = base + 1580;           // 64
    const int u = bid * 2 + half;
    const int b = u >> 9, m = u & (M2 - 1);
    const float* p1 = a.c2_xc + (long)b * XS + 3 * m;
    const float p1x = p1[0], p1y = p1[1], p1z = p1[2];
    const float* p2b = a.c2_xp + (long)b * XS;
    if (hw == 0)
      wave_bq<NS2>(p1x, p1y, p1z, p2b, M2, a.r2c2, sidx, lane);
    else
      wave_bq<NSQ>(p1x, p1y, p1z, a.c2_xc + (long)b * XS, M1, a.r2q2, sfidx, lane);
    __syncthreads();
    if (ht < O1) {
      float bv = -3.0e38f;
#pragma unroll
      for (int s = 0; s < NSQ; ++s)
        bv = fmaxf(bv, a.c2_S1[((long)b * M1 + sfidx[s]) * O1 + ht]);
      feat[ht] = bv;
    }
    __syncthreads();
    for (int e = ht; e < NS2 * C42; e += 128) {
      const int s = e / C42, c = e - s * C42;
      const int j = sidx[s];
      float v;
      if (c < O2) {
        v = a.c2_Sp[((long)b * M2 + j) * O2 + c];
      } else if (c < O2 + O1) {
        v = feat[c - O2];
      } else if (c < C2) {
        const int d = c - O2 - O1;
        v = __fsub_rn(p2b[3 * j + d], (d == 0) ? p1x : ((d == 1) ? p1y : p1z));
      } else {
        v = 0.f;
      }
      corr2[e] = v;
    }
    __syncthreads();
    const float4* wp4 = (const float4*)a.c2_W;
    float accs[NS2];
#pragma unroll
    for (int s = 0; s < NS2; ++s) accs[s] = 0.f;
    for (int q = 0; q < C42 / 4; ++q) {
      const float4 wv = wp4[(long)q * O2 + ht];
#pragma unroll
      for (int s = 0; s < NS2; ++s) {
        const float4 cv = *(const float4*)(corr2 + s * C42 + 4 * q);
        float acc = accs[s];
        acc = fmaf(wv.x, cv.x, acc);
        acc = fmaf(wv.y, cv.y, acc);
        acc = fmaf(wv.z, cv.z, acc);
        acc = fmaf(wv.w, cv.w, acc);
        accs[s] = acc;
      }
    }
    float best = accs[0];
#pragma unroll
    for (int s = 1; s < NS2; ++s) best = fmaxf(best, accs[s]);
    a.c2_Sc[((long)b * M2 + m) * O2 + ht] = best;
    return;
  }
  bid -= a.n2;

  if (bid < a.n3) {  // -------- cell level-3 (1 unit/block, 256 thr) --------
    float* corr2 = smem;                 // [NS3][C43] = 1552
    int* sidx = (int*)(smem + 1552);
    int* sfidx = (int*)(smem + 1556);
    float* feat = smem + 1560;           // 128
    const int b = bid >> 8, m = bid & (M3 - 1);
    const float* p1 = a.c3_xc + (long)b * XS + 3 * m;
    const float p1x = p1[0], p1y = p1[1], p1z = p1[2];
    const float* p2b = a.c3_xp + (long)b * XS;
    if (wave == 0)
      wave_bq<NS3>(p1x, p1y, p1z, p2b, M3, a.r2c3, sidx, lane);
    else if (wave == 1)
      wave_bq<NSQ>(p1x, p1y, p1z, a.c3_xc + (long)b * XS, M2, a.r2q3, sfidx, lane);
    __syncthreads();
    if (tid < O2) {
      float bv = -3.0e38f;
#pragma unroll
      for (int s = 0; s < NSQ; ++s)
        bv = fmaxf(bv, a.c3_S2[((long)b * M2 + sfidx[s]) * O2 + tid]);
      feat[tid] = bv;
    }
    __syncthreads();
    for (int e = tid; e < NS3 * C43; e += 256) {
      const int s = e / C43, c = e - s * C43;
      const int j = sidx[s];
      float v;
      if (c < O3) {
        v = a.c3_Sp[((long)b * M3 + j) * O3 + c];
      } else if (c < O3 + O2) {
        v = feat[c - O3];
      } else if (c < C3) {
        const int d = c - O3 - O2;
        v = __fsub_rn(p2b[3 * j + d], (d == 0) ? p1x : ((d == 1) ? p1y : p1z));
      } else {
        v = 0.f;
      }
      corr2[e] = v;
    }
    __syncthreads();
    const float4* wp4 = (const float4*)a.c3_W;
    float accs[NS3];
#pragma unroll
    for (int s = 0; s < NS3; ++s) accs[s] = 0.f;
    for (int q = 0; q < C43 / 4; ++q) {
      const float4 wv = wp4[(long)q * O3 + tid];
#pragma unroll
      for (int s = 0; s < NS3; ++s) {
        const float4 cv = *(const float4*)(corr2 + s * C43 + 4 * q);
        float acc = accs[s];
        acc = fmaf(wv.x, cv.x, acc);
        acc = fmaf(wv.y, cv.y, acc);
        acc = fmaf(wv.z, cv.z, acc);
        acc = fmaf(wv.w, cv.w, acc);
        accs[s] = acc;
      }
    }
    float best = accs[0];
#pragma unroll
    for (int s = 1; s < NS3; ++s) best = fmaxf(best, accs[s]);
    a.c3_Sc[((long)b * M3 + m) * O3 + tid] = best;
    return;
  }
  bid -= a.n3;

  {  // -------- knn: wave-per-query 3-NN (3584 blocks: 512 + 1024 + 2048) -----
    int q, Mu, Mk;
    const float* unk; long ustr; int* oi; float* ow;
    if (bid < 512) {
      q = bid * 4 + wave; Mu = M2; Mk = M3; unk = a.k_xc; ustr = XS;
      oi = a.ii2; ow = a.iw2;
    } else if (bid < 1536) {
      q = (bid - 512) * 4 + wave; Mu = M1; Mk = M2; unk = a.k_xc; ustr = XS;
      oi = a.ii1; ow = a.iw1;
    } else {
      q = (bid - 1536) * 4 + wave; Mu = N0; Mk = M1; unk = a.k_frame; ustr = 3L * N0;
      oi = a.ii0; ow = a.iw0;
    }
    const int b = q / Mu, m = q - b * Mu;
    const float* qq = unk + (long)b * ustr + (long)m * 3;
    const float qx = qq[0], qy = qq[1], qz = qq[2];
    const float* s = a.k_xc + (long)b * XS;
    unsigned long long k0 = ~0ull, k1 = ~0ull, k2 = ~0ull;
    const int steps = Mk >> 6;
    for (int t7 = 0; t7 < steps; ++t7) {
      const int j = (t7 << 6) + lane;
      const float dd = sq3(qx, qy, qz, s[3 * j], s[3 * j + 1], s[3 * j + 2]);
      const unsigned long long key =
          ((unsigned long long)__float_as_uint(dd) << 32) | (unsigned)j;
      if (key < k0) { k2 = k1; k1 = k0; k0 = key; }
      else if (key < k1) { k2 = k1; k1 = key; }
      else if (key < k2) { k2 = key; }
    }
    float dw[3]; int jw[3];
#pragma unroll
    for (int r = 0; r < 3; ++r) {
      unsigned mhi = (unsigned)(k0 >> 32), mlo = (unsigned)k0;
      dpp_min64_step<0x111>(mhi, mlo);
      dpp_min64_step<0x112>(mhi, mlo);
      dpp_min64_step<0x114>(mhi, mlo);
      dpp_min64_step<0x118>(mhi, mlo);
      dpp_min64_step<0x142>(mhi, mlo);
      dpp_min64_step<0x143>(mhi, mlo);
      const unsigned whi = (unsigned)__builtin_amdgcn_readlane((int)mhi, 63);
      const unsigned wlo = (unsigned)__builtin_amdgcn_readlane((int)mlo, 63);
      const unsigned long long w = ((unsigned long long)whi << 32) | wlo;
      dw[r] = __uint_as_float(whi);
      jw[r] = (int)wlo;
      if (k0 == w) { k0 = k1; k1 = k2; k2 = ~0ull; }
    }
    const float r0 = 1.0f / __fadd_rn(dw[0], 1e-8f);
    const float r1 = 1.0f / __fadd_rn(dw[1], 1e-8f);
    const float r2 = 1.0f / __fadd_rn(dw[2], 1e-8f);
    const float sum = __fadd_rn(__fadd_rn(r0, r1), r2);
    if (lane == 0) {
      ow[q * 3 + 0] = r0 / sum;
      ow[q * 3 + 1] = r1 / sum;
      ow[q * 3 + 2] = r2 / sum;
      oi[q * 3 + 0] = jw[0];
      oi[q * 3 + 1] = jw[1];
      oi[q * 3 + 2] = jw[2];
    }
  }
}

// ---------------- buildl2 (float4 per thread, fully coalesced) ----------------
__global__ __launch_bounds__(256) void buildl2_kernel(const float* __restrict__ S3c,
                                                      const float* __restrict__ S2c,
                                                      const float* __restrict__ S1c,
                                                      const int* __restrict__ ii1,
                                                      const float* __restrict__ iw1,
                                                      const int* __restrict__ ii2,
                                                      const float* __restrict__ iw2,
                                                      float* __restrict__ l2) {
  const int t = blockIdx.x * 256 + threadIdx.x;  // exact: B*M1*112
  const int bm = t / 112;
  const int c0 = (t - bm * 112) * 4;
  const int b = bm >> 10;
  const int* id1 = ii1 + (long)bm * 3;
  const float* w1 = iw1 + (long)bm * 3;
  float4 v;
  if (c0 < O3) {
    float4 v2[3];
#pragma unroll
    for (int k = 0; k < 3; ++k) {
      const int m2 = id1[k];
      const int* id2 = ii2 + ((long)b * M2 + m2) * 3;
      const float* w2 = iw2 + ((long)b * M2 + m2) * 3;
      const float4 s0 = *(const float4*)(S3c + ((long)b * M3 + id2[0]) * O3 + c0);
      const float4 s1 = *(const float4*)(S3c + ((long)b * M3 + id2[1]) * O3 + c0);
      const float4 s2 = *(const float4*)(S3c + ((long)b * M3 + id2[2]) * O3 + c0);
      v2[k] = wsum3(s0, s1, s2, w2[0], w2[1], w2[2]);
    }
    v = wsum3(v2[0], v2[1], v2[2], w1[0], w1[1], w1[2]);
  } else if (c0 < 384) {
    const int cc = c0 - O3;
    const float4 s0 = *(const float4*)(S2c + ((long)b * M2 + id1[0]) * O2 + cc);
    const float4 s1 = *(const float4*)(S2c + ((long)b * M2 + id1[1]) * O2 + cc);
    const float4 s2 = *(const float4*)(S2c + ((long)b * M2 + id1[2]) * O2 + cc);
    v = wsum3(s0, s1, s2, w1[0], w1[1], w1[2]);
  } else {
    v = *(const float4*)(S1c + (long)bm * O1 + (c0 - 384));
  }
  *(float4*)(l2 + (long)bm * 448 + c0) = v;
}

// ---------------- mlp: interp-to-l1 + 2-layer MLP + frame update -------------
__global__ __launch_bounds__(256) void mlp_kernel(const float* __restrict__ l2,
                                                  const int* __restrict__ ii,
                                                  const float* __restrict__ iw,
                                                  const float* __restrict__ W1P,
                                                  const float* __restrict__ b1,
                                                  const float* __restrict__ W2,
                                                  const float* __restrict__ b2,
                                                  float* __restrict__ frame,
                                                  float* __restrict__ out, int td) {
  __shared__ __align__(16) float smem[4 * 512];
  const int lane = threadIdx.x & 63;
  const int wave = threadIdx.x >> 6;
  float* col = smem + (size_t)wave * 512;
  float* h = col + 448;
  const int u = blockIdx.x * 4 + wave;  // exact: B*N0 units
  const int b = u >> 11, n = u & (N0 - 1);
  const int* id = ii + (long)u * 3;
  const float* w = iw + (long)u * 3;
  const float w0 = w[0], w1 = w[1], w2v = w[2];
  const float4* r0 = (const float4*)(l2 + ((long)b * M1 + id[0]) * 448);
  const float4* r1 = (const float4*)(l2 + ((long)b * M1 + id[1]) * 448);
  const float4* r2 = (const float4*)(l2 + ((long)b * M1 + id[2]) * 448);
  float4* col4 = (float4*)col;
  for (int q = lane; q < 112; q += 64)
    col4[q] = wsum3(r0[q], r1[q], r2[q], w0, w1, w2v);
  __builtin_amdgcn_wave_barrier();
  const float4* wp4 = (const float4*)W1P;
  float acc = b1[lane];
  for (int q = 0; q < 112; ++q) {
    const float4 wv = wp4[(long)q * 64 + lane];
    const float4 cv = col4[q];
    acc = fmaf(wv.x, cv.x, acc);
    acc = fmaf(wv.y, cv.y, acc);
    acc = fmaf(wv.z, cv.z, acc);
    acc = fmaf(wv.w, cv.w, acc);
  }
  h[lane] = fmaxf(acc, 0.0f);
  __builtin_amdgcn_wave_barrier();
  if (lane < 3) {
    const float* w2r = W2 + lane * 64;
    float acc2 = b2[lane];
    for (int c = 0; c < 64; ++c) acc2 = fmaf(w2r[c], h[c], acc2);
    const float nf = frame[(long)u * 3 + lane] + acc2;
    frame[(long)u * 3 + lane] = nf;
    out[(((long)b * 4 + td) * N0 + n) * 3 + lane] = nf;
  }
}

extern "C" void kernel_launch(void* const* d_in, const int* in_sizes, int n_in,
                              void* d_out, int out_size, void* d_ws, size_t ws_size,
                              hipStream_t stream) {
  const float* xyzs = (const float*)d_in[0];
  const float* enw[3] = {(const float*)d_in[1], (const float*)d_in[2], (const float*)d_in[3]};
  const float* dew[3] = {(const float*)d_in[4], (const float*)d_in[5], (const float*)d_in[6]};
  const float* mw1 = (const float*)d_in[7];
  const float* mb1 = (const float*)d_in[8];
  const float* mw2 = (const float*)d_in[9];
  const float* mb2 = (const float*)d_in[10];
  float* out = (float*)d_out;

  float* ws = (float*)d_ws;
  size_t off = 0;
  auto alloc = [&](size_t nn) { float* p = ws + off; off += nn; return p; };
  const long st1 = (long)B * M1 * 3;
  float* frame = alloc((size_t)B * N0 * 3);
  float* xyz1e = alloc((size_t)4 * st1);
  float* xyz1d[2] = {alloc((size_t)st1), alloc((size_t)st1)};
  float* z1 = alloc((size_t)st1);
  float* S1bf[2] = {alloc((size_t)B * O1 * M1), alloc((size_t)B * O1 * M1)};
  float* S2bf[2] = {alloc((size_t)B * O2 * M2), alloc((size_t)B * O2 * M2)};
  float* S3bf[2] = {alloc((size_t)B * O3 * M3), alloc((size_t)B * O3 * M3)};
  float* l2 = alloc((size_t)B * 448 * M1);
  float* iw0 = alloc((size_t)B * N0 * 3);
  int* ii0 = (int*)alloc((size_t)B * N0 * 3);
  float* iw1 = alloc((size_t)B * M1 * 3);
  int* ii1 = (int*)alloc((size_t)B * M1 * 3);
  float* iw2 = alloc((size_t)B * M2 * 3);
  int* ii2 = (int*)alloc((size_t)B * M2 * 3);
  float* wt = alloc((size_t)WP_TOT);

  hipMemsetAsync(z1, 0, (size_t)st1 * 4, stream);
  hipMemsetAsync(S1bf[1], 0, (size_t)B * O1 * M1 * 4, stream);
  hipMemsetAsync(S2bf[1], 0, (size_t)B * O2 * M2 * 4, stream);
  hipMemsetAsync(S3bf[1], 0, (size_t)B * O3 * M3 * 4, stream);
  hipMemsetAsync(wt, 0, (size_t)WP_TOT * 4, stream);  // pad weights must be 0

  double r;
  r = 4.0 + 1e-6;             const float r2c1 = (float)(r * r);
  r = 2.0 * 4.0 / 4.0 + 1e-6; const float r2q2 = (float)(r * r);
  r = 2.0 * 4.0 + 1e-6;       const float r2c2 = (float)(r * r);
  r = 4.0 * 4.0 / 4.0 + 1e-6; const float r2q3 = (float)(r * r);
  r = 3.0 * 4.0 + 1e-6;       const float r2c3 = (float)(r * r);

  pack_w<<<dim3((285312 + 255) / 256), 256, 0, stream>>>(
      enw[0], enw[1], enw[2], dew[0], dew[1], dew[2], mw1, wt);

  // encoder FPS (4 timesteps) + merged copyframe (y==4)
  fps8<2048, 1024><<<dim3(B, 5), 256, 0, stream>>>(xyzs, (long)LF * N0 * 3,
                                                   (long)N0 * 3, xyz1e, XS, st1,
                                                   xyzs, frame, 4);

  // t=4: frame == xyzs[:,3] bit-exactly => reuse encoder t=3's FPS result.
  const float* x1_of_t[LF] = {
      xyz1e + 0 * st1, xyz1e + 1 * st1, xyz1e + 2 * st1, xyz1e + 3 * st1,
      xyz1e + 3 * st1, xyz1d[0], xyz1d[1], xyz1d[0]};

  const float* wp1[2] = {wt + WP_E1, wt + WP_D1};
  const float* wp2[2] = {wt + WP_E2, wt + WP_D2};
  const float* wp3[2] = {wt + WP_E3, wt + WP_D3};

  auto launch_fused = [&](int t1, int t2, int t3, int tk) {
    FusedArgs a{};
    int nb = 0;
    if (t1 >= 0) {
      a.n1 = B * M1 / 4;
      a.c1_xc = x1_of_t[t1];
      a.c1_xp = (t1 == 0) ? z1 : x1_of_t[t1 - 1];
      a.c1_W = wp1[t1 >= 4];
      a.c1_Sp = S1bf[1 - (t1 & 1)];
      a.c1_Sc = S1bf[t1 & 1];
      nb += a.n1;
    }
    if (t2 >= 0) {
      a.n2 = B * M2 / 2;
      a.c2_xc = x1_of_t[t2];
      a.c2_xp = (t2 == 0) ? z1 : x1_of_t[t2 - 1];
      a.c2_W = wp2[t2 >= 4];
      a.c2_Sp = S2bf[1 - (t2 & 1)];
      a.c2_S1 = S1bf[t2 & 1];
      a.c2_Sc = S2bf[t2 & 1];
      nb += a.n2;
    }
    if (t3 >= 0) {
      a.n3 = B * M3;
      a.c3_xc = x1_of_t[t3];
      a.c3_xp = (t3 == 0) ? z1 : x1_of_t[t3 - 1];
      a.c3_W = wp3[t3 >= 4];
      a.c3_Sp = S3bf[1 - (t3 & 1)];
      a.c3_S2 = S2bf[t3 & 1];
      a.c3_Sc = S3bf[t3 & 1];
      nb += a.n3;
    }
    if (tk >= 0) {
      a.nk = 3584;  // wave-per-query: 512 (ii2) + 1024 (ii1) + 2048 (ii0) blocks
      a.k_xc = x1_of_t[tk];
      a.k_frame = frame;
      a.ii2 = ii2; a.ii1 = ii1; a.ii0 = ii0;
      a.iw2 = iw2; a.iw1 = iw1; a.iw0 = iw0;
      nb += a.nk;
    }
    a.r2c1 = r2c1; a.r2c2 = r2c2; a.r2q2 = r2q2; a.r2c3 = r2c3; a.r2q3 = r2q3;
    fused_cells<<<dim3((unsigned)nb), 256, 0, stream>>>(a);
  };

  auto tail = [&](int t) {
    buildl2_kernel<<<dim3(B * M1 * 112 / 256), 256, 0, stream>>>(
        S3bf[t & 1], S2bf[t & 1], S1bf[t & 1], ii1, iw1, ii2, iw2, l2);
    mlp_kernel<<<dim3(B * N0 / 4), 256, 0, stream>>>(
        l2, ii0, iw0, wt + WP_M1, mb1, mw2, mb2, frame, out, t - 4);
  };

  // encoder software pipeline + t=4 head (diagonal: independent tasks merged)
  launch_fused(0, -1, -1, -1);
  launch_fused(1, 0, -1, -1);
  launch_fused(2, 1, 0, -1);
  launch_fused(3, 2, 1, -1);
  launch_fused(4, 3, 2, 4);
  launch_fused(-1, 4, 3, -1);
  launch_fused(-1, -1, 4, -1);
  tail(4);

  for (int t = 5; t < LF; ++t) {
    fps8<2048, 1024><<<dim3(B, 1), 256, 0, stream>>>(frame, (long)N0 * 3, 0,
                                                     (float*)x1_of_t[t], XS, 0,
                                                     nullptr, nullptr, -1);
    launch_fused(t, -1, -1, t);
    launch_fused(-1, t, -1, -1);
    launch_fused(-1, -1, t, -1);
    tail(t);
  }
  (void)in_sizes; (void)n_in; (void)out_size; (void)ws_size;
}